// Round 5
// baseline (747.833 us; speedup 1.0000x reference)
//
#include <hip/hip_runtime.h>
#include <cstdint>

#define B_ 4096
#define F_ 1024
#define H_ 16384
#define TOPK 64
#define MAXC 192
// 2E: twice the bound on |a_fp16_stored - a_ref|.
// fp16-GEMM error <= 0.0031 (bf16's proven 0.025 scaled by 2^-3) +
// fp16 storage rounding <= 0.002  => E=0.010 gives ~2x headroom.
#define TWOE 0.020f

typedef unsigned short u16;
typedef __attribute__((ext_vector_type(8))) _Float16 f16x8;
typedef __attribute__((ext_vector_type(8))) unsigned short u16x8;
typedef __attribute__((ext_vector_type(4))) float f32x4;

__device__ __forceinline__ u16 f2bf(float f) {
  union { float f; uint32_t u; } v; v.f = f;
  uint32_t u = v.u;
  uint32_t r = u + 0x7FFFu + ((u >> 16) & 1u);
  return (u16)(r >> 16);
}
__device__ __forceinline__ float bf2f(u16 h) {
  union { uint32_t u; float f; } v; v.u = ((uint32_t)h) << 16; return v.f;
}
__device__ __forceinline__ u16 f2h(float f) {
  union { _Float16 h; u16 u; } v; v.h = (_Float16)f; return v.u;
}
__device__ __forceinline__ float h2f(u16 h) {
  union { _Float16 h; u16 u; } v; v.u = h; return (float)v.h;
}
// packed pair of fp16: zero any negative half (key space: monotone for >=0)
__device__ __forceinline__ uint32_t key2(uint32_t v) {
  uint32_t s = (v >> 15) & 0x00010001u;
  return v & ~(s * 0xFFFFu);
}

__device__ __forceinline__ void async16(const void* g, void* l) {
  __builtin_amdgcn_global_load_lds(
      reinterpret_cast<const __attribute__((address_space(1))) uint32_t*>(
          reinterpret_cast<uintptr_t>(g)),
      reinterpret_cast<__attribute__((address_space(3))) uint32_t*>(
          reinterpret_cast<uintptr_t>(l)),
      16, 0, 0);
}

// ---- K0a: xbar = fp16(x - b_dec) ----
__global__ __launch_bounds__(256) void k_xbar(const float* __restrict__ x,
                                              const float* __restrict__ b_dec,
                                              u16* __restrict__ xbar) {
  int i = blockIdx.x * 256 + threadIdx.x;
  int base = i * 4;
  int col = base & (F_ - 1);
  float4 xv = *(const float4*)(x + base);
  float4 bv = *(const float4*)(b_dec + col);
  ushort4 o;
  o.x = f2h(xv.x - bv.x); o.y = f2h(xv.y - bv.y);
  o.z = f2h(xv.z - bv.z); o.w = f2h(xv.w - bv.w);
  *(ushort4*)(xbar + base) = o;
}

// ---- K0b: fp16 cast of W_enc ----
__global__ __launch_bounds__(256) void k_cast(const float* __restrict__ src,
                                              u16* __restrict__ dst) {
  size_t base = (size_t)(blockIdx.x * 256 + threadIdx.x) * 4;
  float4 v = *(const float4*)(src + base);
  ushort4 o; o.x = f2h(v.x); o.y = f2h(v.y); o.z = f2h(v.z); o.w = f2h(v.w);
  *(ushort4*)(dst + base) = o;
}

// ---- K0c: W_dec [F,H] fp32 -> W_decT [H,F] bf16 (decode path unchanged) ----
__global__ __launch_bounds__(256) void k_transpose(const float* __restrict__ Wdec,
                                                   u16* __restrict__ WdecT) {
  __shared__ float tile[32][33];
  int hb = blockIdx.x * 32, fb = blockIdx.y * 32;
  int tx = threadIdx.x & 31, ty = threadIdx.x >> 5;  // ty 0..7
#pragma unroll
  for (int i = 0; i < 32; i += 8)
    tile[ty + i][tx] = Wdec[(size_t)(fb + ty + i) * H_ + hb + tx];
  __syncthreads();
#pragma unroll
  for (int i = 0; i < 32; i += 8)
    WdecT[(size_t)(hb + ty + i) * F_ + fb + tx] = f2bf(tile[tx][ty + i]);
}

// ---- K1: fp16 MFMA GEMM, minimum-2-phase double-buffer (T3-min recipe):
// stage tile t+1 BEFORE compute of tile t; ONE __syncthreads per tile (its
// implicit vmcnt(0) drains the stage). Numerics bit-identical to round-4.
// Launched as TWO half-grids (by0 = 0 / 16) so the next-biggest kernel
// becomes visible in the profile top-5 (instrumentation, ~free).
__device__ __forceinline__ void gemm_step(const u16* __restrict__ bA,
                                          const u16* __restrict__ bB,
                                          int aoff, int boff, int kcp,
                                          f32x4 (&acc)[4][4]) {
  f16x8 av[4], bv[4];
#pragma unroll
  for (int i = 0; i < 4; ++i)
    av[i] = *(const f16x8*)&bA[(aoff + i * 16) * 32 + kcp];
#pragma unroll
  for (int j = 0; j < 4; ++j)
    bv[j] = *(const f16x8*)&bB[(boff + j * 16) * 32 + kcp];
#pragma unroll
  for (int i = 0; i < 4; ++i)
#pragma unroll
    for (int j = 0; j < 4; ++j)
      acc[i][j] = __builtin_amdgcn_mfma_f32_16x16x32_f16(av[i], bv[j], acc[i][j], 0, 0, 0);
}

__global__ __launch_bounds__(256) void k_gemm(const u16* __restrict__ A,
                                              const u16* __restrict__ Bm,
                                              const float* __restrict__ b_enc,
                                              u16* __restrict__ Cf16,
                                              float* __restrict__ fzero,
                                              int by0) {
  __shared__ u16 lA[2][128 * 32];
  __shared__ u16 lB[2][128 * 32];
  const int tid = threadIdx.x;
  const int lane = tid & 63, wave = tid >> 6;
  const int wm = wave >> 1, wn = wave & 1;
  const int bx = blockIdx.x, by = by0 + blockIdx.y;

  const int kcs = (tid & 3) ^ ((tid >> 3) & 3);  // swizzled source chunk
  const u16* gA0 = A + (size_t)(by * 128 + (tid >> 2)) * F_ + kcs * 8;
  const u16* gB0 = Bm + (size_t)(bx * 128 + (tid >> 2)) * F_ + kcs * 8;

#define STAGE(b_, k0_)                                       \
  {                                                          \
    async16(gA0 + (k0_), &lA[b_][tid * 8]);                  \
    async16(gA0 + 64 * F_ + (k0_), &lA[b_][tid * 8 + 2048]); \
    async16(gB0 + (k0_), &lB[b_][tid * 8]);                  \
    async16(gB0 + 64 * F_ + (k0_), &lB[b_][tid * 8 + 2048]); \
  }

  f32x4 acc[4][4] = {};
  const int lm = lane & 15;
  const int kcp = (((lane >> 4) ^ ((lm >> 1) & 3))) * 8;  // swizzled read offset
  const int aoff = wm * 64 + lm, boff = wn * 64 + lm;

  STAGE(0, 0);
  __syncthreads();  // vmcnt(0) drain: tile 0 resident
  int cur = 0;
#pragma unroll 1
  for (int t = 0; t < 31; ++t) {
    STAGE(cur ^ 1, (t + 1) * 32);               // issue next tile first
    gemm_step(lA[cur], lB[cur], aoff, boff, kcp, acc);  // overlap compute
    __syncthreads();                            // drains stage; swap safe
    cur ^= 1;
  }
  gemm_step(lA[cur], lB[cur], aoff, boff, kcp, acc);  // tile 31
#undef STAGE

  // zero-fill slice of f's first half: 4096 block-slots x 32 KB = 128 MB
  {
    const int bid = by * 128 + bx;  // 0..4095 across both half-grids
    float* zp = fzero + (size_t)bid * 8192 + tid * 4;
    const f32x4 z4 = {0.f, 0.f, 0.f, 0.f};
#pragma unroll
    for (int k = 0; k < 8; ++k)
      __builtin_nontemporal_store(z4, (f32x4*)(zp + k * 1024));
  }

#pragma unroll
  for (int i = 0; i < 4; ++i) {
    int rowg = by * 128 + wm * 64 + i * 16 + (lane >> 4) * 4;
#pragma unroll
    for (int j = 0; j < 4; ++j) {
      int colg = bx * 128 + wn * 64 + j * 16 + lm;
      float be = b_enc[colg];
      u16* cp = Cf16 + (size_t)rowg * H_ + colg;
#pragma unroll
      for (int r = 0; r < 4; ++r)
        cp[(size_t)r * H_] = f2h(acc[i][j][r] + be);
    }
  }
}

// ---- K2: fused select + refine (round-4 passing version; binary search now
// one barrier per iteration via double-buffered count slots) ----
__global__ __launch_bounds__(256) void k_selref(const u16* __restrict__ af16,
                                                const float* __restrict__ x,
                                                const float* __restrict__ b_dec,
                                                const float* __restrict__ Wenc,
                                                const float* __restrict__ b_enc,
                                                int* __restrict__ decIdx,
                                                float* __restrict__ decVal) {
  const int row = blockIdx.x, tid = threadIdx.x;
  const int lane = tid & 63, wave = tid >> 6;
  __shared__ float wbuf[4][2][F_];  // 32 KB refine gather buffers
  __shared__ float xs[F_];          // 4 KB
  __shared__ double vals[MAXC];     // 1.5 KB
  __shared__ float bes[MAXC];
  __shared__ int idxs[MAXC];
  __shared__ int s_cnt8[2][4];
  __shared__ int s_sure, s_amb;

  if (tid == 0) { s_sure = 0; s_amb = 0; idxs[0] = 0; }
  for (int k = tid; k < F_; k += 256)
    xs[k] = x[(size_t)row * F_ + k] - b_dec[k];

  // row -> registers as sort keys (64 halfs = 32 packed u32 per thread)
  uint32_t pr[32];
  {
    const uint4* arow16 = (const uint4*)(af16 + (size_t)row * H_);
#pragma unroll
    for (int j = 0; j < 8; ++j) {
      uint4 v = arow16[tid + 256 * j];
      pr[j * 4 + 0] = key2(v.x);
      pr[j * 4 + 1] = key2(v.y);
      pr[j * 4 + 2] = key2(v.z);
      pr[j * 4 + 3] = key2(v.w);
    }
  }

  // binary search largest t with count(key >= t) >= TOPK  ->  t = stored v64
  uint32_t lo = 0, hi = 0x7C00;  // count(>=0)=16384 >= 64 > count(>=inf)=0
  int it = 0;
  while (hi - lo > 1) {
    const uint32_t mid = (lo + hi) >> 1;
    int c = 0;
#pragma unroll
    for (int r = 0; r < 32; ++r) {
      c += ((pr[r] & 0xFFFFu) >= mid);
      c += ((pr[r] >> 16) >= mid);
    }
#pragma unroll
    for (int off = 32; off > 0; off >>= 1) c += __shfl_xor(c, off);
    if (lane == 0) s_cnt8[it & 1][wave] = c;
    __syncthreads();
    const int* sc = s_cnt8[it & 1];
    const int tot = sc[0] + sc[1] + sc[2] + sc[3];
    if (tot >= TOPK) lo = mid; else hi = mid;
    ++it;  // next iter writes the other slot; this slot re-written only
           // after the NEXT barrier -> no second barrier needed
  }
  const float v64f = h2f((u16)lo);
  const float sc = v64f + TWOE;  // stored >  sc: surely in top-64
  const float al = v64f - TWOE;  // stored <  al: surely out

  int* dI = decIdx + row * TOPK;
  float* dV = decVal + row * TOPK;
#pragma unroll
  for (int j = 0; j < 8; ++j) {
#pragma unroll
    for (int w = 0; w < 4; ++w) {
      const uint32_t v = pr[j * 4 + w];
      const int ib = (tid + 256 * j) * 8 + w * 2;
      const float f0 = h2f((u16)(v & 0xFFFFu));
      const float f1 = h2f((u16)(v >> 16));
      if (f0 > sc) {
        int p = atomicAdd(&s_sure, 1);
        if (p < TOPK) { dI[p] = ib; dV[p] = f0 > 0.f ? f0 : 0.f; }
      } else if (f0 >= al) {
        int p = atomicAdd(&s_amb, 1);
        if (p < MAXC) idxs[p] = ib;
      }
      if (f1 > sc) {
        int p = atomicAdd(&s_sure, 1);
        if (p < TOPK) { dI[p] = ib + 1; dV[p] = f1 > 0.f ? f1 : 0.f; }
      } else if (f1 >= al) {
        int p = atomicAdd(&s_amb, 1);
        if (p < MAXC) idxs[p] = ib + 1;
      }
    }
  }
  __syncthreads();
  const int S = s_sure < TOPK ? s_sure : TOPK;
  const int cnt = s_amb < MAXC ? s_amb : MAXC;
  for (int c = tid; c < cnt; c += 256) bes[c] = b_enc[idxs[c]];
  __syncthreads();

  // candidate-invariant x slice -> fp32 registers
  float xr[16];
#pragma unroll
  for (int ch = 0; ch < 4; ++ch)
#pragma unroll
    for (int j = 0; j < 4; ++j)
      xr[ch * 4 + j] = xs[ch * 256 + lane * 4 + j];

#define ISSUE_ROW(c_, b_)                                                  \
  {                                                                        \
    int cc_ = (c_) < cnt ? (c_) : 0;                                       \
    const float* src_ = Wenc + (size_t)idxs[cc_] * F_ + lane * 4;          \
    float* dst_ = &wbuf[wave][(b_)][lane * 4];                             \
    async16(src_ + 0, dst_ + 0);                                           \
    async16(src_ + 256, dst_ + 256);                                       \
    async16(src_ + 512, dst_ + 512);                                       \
    async16(src_ + 768, dst_ + 768);                                       \
  }

  const int nIter = (cnt - wave + 3) / 4;
  ISSUE_ROW(wave, 0);
  ISSUE_ROW(wave + 4, 1);

  for (int i = 0; i < nIter; ++i) {
    const int c = wave + i * 4;
    const int bsel = i & 1;
    asm volatile("s_waitcnt vmcnt(4)" ::: "memory");
    __builtin_amdgcn_sched_barrier(0);

    const float4* wr = (const float4*)wbuf[wave][bsel];
    double s = 0.0;
#pragma unroll
    for (int ch = 0; ch < 4; ++ch) {
      float4 wv = wr[ch * 64 + lane];
      s = fma((double)xr[ch * 4 + 0], (double)wv.x, s);
      s = fma((double)xr[ch * 4 + 1], (double)wv.y, s);
      s = fma((double)xr[ch * 4 + 2], (double)wv.z, s);
      s = fma((double)xr[ch * 4 + 3], (double)wv.w, s);
    }
    __builtin_amdgcn_sched_barrier(0);
    ISSUE_ROW(wave + (i + 2) * 4, bsel);

#pragma unroll
    for (int off = 32; off > 0; off >>= 1) s += __shfl_xor(s, off);
    if (lane == 0 && c < cnt) vals[c] = s + (double)bes[c];
  }
#undef ISSUE_ROW
  __syncthreads();

  // exact ranking among ambiguous; top (TOPK - S) win slots S..TOPK-1
  const int Kp = TOPK - S;
  for (int c = tid; c < cnt; c += 256) {
    const double v = vals[c];
    const int h = idxs[c];
    int rank = 0;
    for (int o = 0; o < cnt; ++o) {
      double vo = vals[o];
      rank += (vo > v) || (vo == v && idxs[o] < h);  // jax tie-break
    }
    if (rank < Kp) {
      float fv = v > 0.0 ? (float)v : 0.0f;
      dI[S + rank] = h;
      dV[S + rank] = fv;
    }
  }
}

// ---- K3: zero f second half + scatter f + sparse decode.
// Gather rebuilt: 16 B/lane (ushort8), TWO rows per iteration (threads
// 0-127 even rows / 128-255 odd rows, each thread owns 8 columns), parity
// partials combined via 4 KB LDS at the end. Halves loop trips, widens
// transactions, unroll-8 keeps 8x16B in flight per thread.
__global__ __launch_bounds__(256) void k_decode(const int* __restrict__ decIdx,
                                               const float* __restrict__ decVal,
                                               const u16* __restrict__ WdecT,
                                               const float* __restrict__ b_dec,
                                               float* __restrict__ f,
                                               float* __restrict__ xhat) {
  const int row = blockIdx.x, tid = threadIdx.x;
  __shared__ int sIdx[TOPK];
  __shared__ float sVal[TOPK];
  __shared__ float part[F_];  // 4 KB parity partials
  if (tid < TOPK) {
    sIdx[tid] = decIdx[row * TOPK + tid] & (H_ - 1);  // mask: fault-proof
    sVal[tid] = decVal[row * TOPK + tid];
  }
  float* frow = f + (size_t)row * H_;
  if (row >= B_ / 2) {  // second half held af16; now dead -> zero it here
    const f32x4 z4 = {0.f, 0.f, 0.f, 0.f};
    for (int i = tid; i < H_ / 4; i += 256)
      __builtin_nontemporal_store(z4, (f32x4*)frow + i);
  }
  __syncthreads();  // drains vmcnt: zeros committed before scatter
  if (tid < TOPK) frow[sIdx[tid]] = sVal[tid];

  const int cb = (tid & 127) * 8;  // owned column base (8 cols)
  const int par = tid >> 7;        // row parity
  float a[8] = {0.f, 0.f, 0.f, 0.f, 0.f, 0.f, 0.f, 0.f};
#pragma unroll 8
  for (int j2 = 0; j2 < TOPK / 2; ++j2) {
    const int j = j2 * 2 + par;
    const float v = sVal[j];
    const u16x8 w = *(const u16x8*)(WdecT + (size_t)sIdx[j] * F_ + cb);
#pragma unroll
    for (int k = 0; k < 8; ++k) a[k] += v * bf2f(w[k]);
  }
  if (par) {
#pragma unroll
    for (int k = 0; k < 8; ++k) part[cb + k] = a[k];
  }
  __syncthreads();
  if (!par) {
    float4 bd0 = *(const float4*)(b_dec + cb);
    float4 bd1 = *(const float4*)(b_dec + cb + 4);
    float4 o0, o1;
    o0.x = a[0] + part[cb + 0] + bd0.x;
    o0.y = a[1] + part[cb + 1] + bd0.y;
    o0.z = a[2] + part[cb + 2] + bd0.z;
    o0.w = a[3] + part[cb + 3] + bd0.w;
    o1.x = a[4] + part[cb + 4] + bd1.x;
    o1.y = a[5] + part[cb + 5] + bd1.y;
    o1.z = a[6] + part[cb + 6] + bd1.z;
    o1.w = a[7] + part[cb + 7] + bd1.w;
    float* xp = xhat + (size_t)row * F_ + cb;
    *(float4*)xp = o0;
    *(float4*)(xp + 4) = o1;
  }
}

extern "C" void kernel_launch(void* const* d_in, const int* in_sizes, int n_in,
                              void* d_out, int out_size, void* d_ws, size_t ws_size,
                              hipStream_t stream) {
  const float* x    = (const float*)d_in[0];
  const float* Wenc = (const float*)d_in[1];
  const float* benc = (const float*)d_in[2];
  const float* Wdec = (const float*)d_in[3];
  const float* bdec = (const float*)d_in[4];

  float* out  = (float*)d_out;
  float* f    = out;                       // [4096][16384] fp32
  float* xhat = out + (size_t)B_ * H_;     // [4096][1024]
  // fp16 'a' lives in the upper half of the f region (fully consumed by
  // k_selref before k_decode zero-fills that half) — no ws growth.
  u16* af16 = (u16*)(f + (size_t)B_ * H_ / 2);  // 128 MB

  char* ws = (char*)d_ws;
  u16*  xbar    = (u16*)ws;                             // 8 MB (fp16)
  u16*  wencb   = (u16*)(ws + (size_t)(8)  * 1048576);  // 32 MB (fp16)
  u16*  wdecT   = (u16*)(ws + (size_t)(40) * 1048576);  // 32 MB (bf16)
  int*  decIdx  = (int*)(ws + (size_t)(76) * 1048576);  // 1 MB
  float* decVal = (float*)(ws + (size_t)(77) * 1048576);// 1 MB

  k_xbar<<<B_ * F_ / 1024, 256, 0, stream>>>(x, bdec, xbar);
  k_cast<<<H_ * F_ / 1024, 256, 0, stream>>>(Wenc, wencb);
  k_transpose<<<dim3(H_ / 32, F_ / 32), 256, 0, stream>>>(Wdec, wdecT);
  k_gemm<<<dim3(H_ / 128, B_ / 256), 256, 0, stream>>>(xbar, wencb, benc, af16, f, 0);
  k_gemm<<<dim3(H_ / 128, B_ / 256), 256, 0, stream>>>(xbar, wencb, benc, af16, f, 16);
  k_selref<<<B_, 256, 0, stream>>>(af16, x, bdec, Wenc, benc, decIdx, decVal);
  k_decode<<<B_, 256, 0, stream>>>(decIdx, decVal, wdecT, bdec, f, xhat);
}

// Round 6
// 728.591 us; speedup vs baseline: 1.0264x; 1.0264x over previous
//
#include <hip/hip_runtime.h>
#include <cstdint>

#define B_ 4096
#define F_ 1024
#define H_ 16384
#define TOPK 64
#define MAXC 192
// 2E: twice the bound on |a_fp16_stored - a_ref|.
// fp16-GEMM error <= 0.0031 (bf16's proven 0.025 scaled by 2^-3) +
// fp16 storage rounding <= 0.002  => E=0.010 gives ~2x headroom.
#define TWOE 0.020f

typedef unsigned short u16;
typedef __attribute__((ext_vector_type(8))) _Float16 f16x8;
typedef __attribute__((ext_vector_type(8))) unsigned short u16x8;
typedef __attribute__((ext_vector_type(4))) float f32x4;

__device__ __forceinline__ u16 f2bf(float f) {
  union { float f; uint32_t u; } v; v.f = f;
  uint32_t u = v.u;
  uint32_t r = u + 0x7FFFu + ((u >> 16) & 1u);
  return (u16)(r >> 16);
}
__device__ __forceinline__ float bf2f(u16 h) {
  union { uint32_t u; float f; } v; v.u = ((uint32_t)h) << 16; return v.f;
}
__device__ __forceinline__ u16 f2h(float f) {
  union { _Float16 h; u16 u; } v; v.h = (_Float16)f; return v.u;
}
__device__ __forceinline__ float h2f(u16 h) {
  union { _Float16 h; u16 u; } v; v.u = h; return (float)v.h;
}
// packed pair of fp16: zero any negative half (key space: monotone for >=0)
__device__ __forceinline__ uint32_t key2(uint32_t v) {
  uint32_t s = (v >> 15) & 0x00010001u;
  return v & ~(s * 0xFFFFu);
}

__device__ __forceinline__ void async16(const void* g, void* l) {
  __builtin_amdgcn_global_load_lds(
      reinterpret_cast<const __attribute__((address_space(1))) uint32_t*>(
          reinterpret_cast<uintptr_t>(g)),
      reinterpret_cast<__attribute__((address_space(3))) uint32_t*>(
          reinterpret_cast<uintptr_t>(l)),
      16, 0, 0);
}

// ---- K0a: xbar = fp16(x - b_dec) ----
__global__ __launch_bounds__(256) void k_xbar(const float* __restrict__ x,
                                              const float* __restrict__ b_dec,
                                              u16* __restrict__ xbar) {
  int i = blockIdx.x * 256 + threadIdx.x;
  int base = i * 4;
  int col = base & (F_ - 1);
  float4 xv = *(const float4*)(x + base);
  float4 bv = *(const float4*)(b_dec + col);
  ushort4 o;
  o.x = f2h(xv.x - bv.x); o.y = f2h(xv.y - bv.y);
  o.z = f2h(xv.z - bv.z); o.w = f2h(xv.w - bv.w);
  *(ushort4*)(xbar + base) = o;
}

// ---- K0b: fp16 cast of W_enc ----
__global__ __launch_bounds__(256) void k_cast(const float* __restrict__ src,
                                              u16* __restrict__ dst) {
  size_t base = (size_t)(blockIdx.x * 256 + threadIdx.x) * 4;
  float4 v = *(const float4*)(src + base);
  ushort4 o; o.x = f2h(v.x); o.y = f2h(v.y); o.z = f2h(v.z); o.w = f2h(v.w);
  *(ushort4*)(dst + base) = o;
}

// ---- K0c: W_dec [F,H] fp32 -> W_decT [H,F] bf16 (decode path unchanged) ----
__global__ __launch_bounds__(256) void k_transpose(const float* __restrict__ Wdec,
                                                   u16* __restrict__ WdecT) {
  __shared__ float tile[32][33];
  int hb = blockIdx.x * 32, fb = blockIdx.y * 32;
  int tx = threadIdx.x & 31, ty = threadIdx.x >> 5;  // ty 0..7
#pragma unroll
  for (int i = 0; i < 32; i += 8)
    tile[ty + i][tx] = Wdec[(size_t)(fb + ty + i) * H_ + hb + tx];
  __syncthreads();
#pragma unroll
  for (int i = 0; i < 32; i += 8)
    WdecT[(size_t)(hb + ty + i) * F_ + fb + tx] = f2bf(tile[tx][ty + i]);
}

// ---- K1: fp16 MFMA GEMM, 2-phase double-buffer, single dispatch.
// Zero-fill epilogue REMOVED (first-half zeros moved to k_selrefdec entry;
// second-half to k_zs) -- gemm no longer spends HBM BW on 128 MB of zeros.
__device__ __forceinline__ void gemm_step(const u16* __restrict__ bA,
                                          const u16* __restrict__ bB,
                                          int aoff, int boff, int kcp,
                                          f32x4 (&acc)[4][4]) {
  f16x8 av[4], bv[4];
#pragma unroll
  for (int i = 0; i < 4; ++i)
    av[i] = *(const f16x8*)&bA[(aoff + i * 16) * 32 + kcp];
#pragma unroll
  for (int j = 0; j < 4; ++j)
    bv[j] = *(const f16x8*)&bB[(boff + j * 16) * 32 + kcp];
#pragma unroll
  for (int i = 0; i < 4; ++i)
#pragma unroll
    for (int j = 0; j < 4; ++j)
      acc[i][j] = __builtin_amdgcn_mfma_f32_16x16x32_f16(av[i], bv[j], acc[i][j], 0, 0, 0);
}

__global__ __launch_bounds__(256) void k_gemm(const u16* __restrict__ A,
                                              const u16* __restrict__ Bm,
                                              const float* __restrict__ b_enc,
                                              u16* __restrict__ Cf16) {
  __shared__ u16 lA[2][128 * 32];
  __shared__ u16 lB[2][128 * 32];
  const int tid = threadIdx.x;
  const int lane = tid & 63, wave = tid >> 6;
  const int wm = wave >> 1, wn = wave & 1;
  const int bx = blockIdx.x, by = blockIdx.y;

  const int kcs = (tid & 3) ^ ((tid >> 3) & 3);  // swizzled source chunk
  const u16* gA0 = A + (size_t)(by * 128 + (tid >> 2)) * F_ + kcs * 8;
  const u16* gB0 = Bm + (size_t)(bx * 128 + (tid >> 2)) * F_ + kcs * 8;

#define STAGE(b_, k0_)                                       \
  {                                                          \
    async16(gA0 + (k0_), &lA[b_][tid * 8]);                  \
    async16(gA0 + 64 * F_ + (k0_), &lA[b_][tid * 8 + 2048]); \
    async16(gB0 + (k0_), &lB[b_][tid * 8]);                  \
    async16(gB0 + 64 * F_ + (k0_), &lB[b_][tid * 8 + 2048]); \
  }

  f32x4 acc[4][4] = {};
  const int lm = lane & 15;
  const int kcp = (((lane >> 4) ^ ((lm >> 1) & 3))) * 8;  // swizzled read offset
  const int aoff = wm * 64 + lm, boff = wn * 64 + lm;

  STAGE(0, 0);
  __syncthreads();  // vmcnt(0) drain: tile 0 resident
  int cur = 0;
#pragma unroll 1
  for (int t = 0; t < 31; ++t) {
    STAGE(cur ^ 1, (t + 1) * 32);               // issue next tile first
    gemm_step(lA[cur], lB[cur], aoff, boff, kcp, acc);  // overlap compute
    __syncthreads();                            // drains stage; swap safe
    cur ^= 1;
  }
  gemm_step(lA[cur], lB[cur], aoff, boff, kcp, acc);  // tile 31
#undef STAGE

#pragma unroll
  for (int i = 0; i < 4; ++i) {
    int rowg = by * 128 + wm * 64 + i * 16 + (lane >> 4) * 4;
#pragma unroll
    for (int j = 0; j < 4; ++j) {
      int colg = bx * 128 + wn * 64 + j * 16 + lm;
      float be = b_enc[colg];
      u16* cp = Cf16 + (size_t)rowg * H_ + colg;
#pragma unroll
      for (int r = 0; r < 4; ++r)
        cp[(size_t)r * H_] = f2h(acc[i][j][r] + be);
    }
  }
}

// ---- K2: fused select + refine + DECODE (one block per row).
// Merge rationale: decode's only input is the row-local top-64 list, which
// now stays in LDS (fIdx/fVal); the WdecT gather overlaps the refine tail;
// one ~250-300us dispatch also outranks the harness fill kernels in the
// profile top-5 (visibility). Rows <2048 additionally zero-fill their own
// f row at entry (first half; no af16 alias) during the VALU-heavy search.
__global__ __launch_bounds__(256) void k_selrefdec(const u16* __restrict__ af16,
                                                   const float* __restrict__ x,
                                                   const float* __restrict__ b_dec,
                                                   const float* __restrict__ Wenc,
                                                   const float* __restrict__ b_enc,
                                                   const u16* __restrict__ WdecT,
                                                   float* __restrict__ f,
                                                   float* __restrict__ xhat,
                                                   int* __restrict__ decIdx,
                                                   float* __restrict__ decVal) {
  const int row = blockIdx.x, tid = threadIdx.x;
  const int lane = tid & 63, wave = tid >> 6;
  __shared__ float wbuf[4][2][F_];  // 32 KB refine gather buffers
  __shared__ float xs[F_];          // 4 KB; reused as decode parity partials
  __shared__ double vals[MAXC];     // 1.5 KB
  __shared__ float bes[MAXC];
  __shared__ int idxs[MAXC];
  __shared__ int fIdx[TOPK];        // final top-64 (LDS-resident for decode)
  __shared__ float fVal[TOPK];
  __shared__ int s_cnt8[2][4];
  __shared__ int s_sure, s_amb;

  if (tid == 0) { s_sure = 0; s_amb = 0; idxs[0] = 0; }
  if (tid < TOPK) { fIdx[tid] = 0; fVal[tid] = 0.f; }
  for (int k = tid; k < F_; k += 256)
    xs[k] = x[(size_t)row * F_ + k] - b_dec[k];

  float* frow = f + (size_t)row * H_;
  if (row < B_ / 2) {  // first half: zero own row now (hidden under search)
    const f32x4 z4 = {0.f, 0.f, 0.f, 0.f};
    for (int i = tid; i < H_ / 4; i += 256)
      __builtin_nontemporal_store(z4, (f32x4*)frow + i);
  }

  // row -> registers as sort keys (64 halfs = 32 packed u32 per thread)
  uint32_t pr[32];
  {
    const uint4* arow16 = (const uint4*)(af16 + (size_t)row * H_);
#pragma unroll
    for (int j = 0; j < 8; ++j) {
      uint4 v = arow16[tid + 256 * j];
      pr[j * 4 + 0] = key2(v.x);
      pr[j * 4 + 1] = key2(v.y);
      pr[j * 4 + 2] = key2(v.z);
      pr[j * 4 + 3] = key2(v.w);
    }
  }

  // binary search largest t with count(key >= t) >= TOPK  ->  t = stored v64
  uint32_t lo = 0, hi = 0x7C00;
  int it = 0;
  while (hi - lo > 1) {
    const uint32_t mid = (lo + hi) >> 1;
    int c = 0;
#pragma unroll
    for (int r = 0; r < 32; ++r) {
      c += ((pr[r] & 0xFFFFu) >= mid);
      c += ((pr[r] >> 16) >= mid);
    }
#pragma unroll
    for (int off = 32; off > 0; off >>= 1) c += __shfl_xor(c, off);
    if (lane == 0) s_cnt8[it & 1][wave] = c;
    __syncthreads();
    const int* scp = s_cnt8[it & 1];
    const int tot = scp[0] + scp[1] + scp[2] + scp[3];
    if (tot >= TOPK) lo = mid; else hi = mid;
    ++it;  // double-buffered slot: safe with one barrier per iter
  }
  const float v64f = h2f((u16)lo);
  const float sc = v64f + TWOE;  // stored >  sc: surely in top-64
  const float al = v64f - TWOE;  // stored <  al: surely out

#pragma unroll
  for (int j = 0; j < 8; ++j) {
#pragma unroll
    for (int w = 0; w < 4; ++w) {
      const uint32_t v = pr[j * 4 + w];
      const int ib = (tid + 256 * j) * 8 + w * 2;
      const float f0 = h2f((u16)(v & 0xFFFFu));
      const float f1 = h2f((u16)(v >> 16));
      if (f0 > sc) {
        int p = atomicAdd(&s_sure, 1);
        if (p < TOPK) { fIdx[p] = ib; fVal[p] = f0 > 0.f ? f0 : 0.f; }
      } else if (f0 >= al) {
        int p = atomicAdd(&s_amb, 1);
        if (p < MAXC) idxs[p] = ib;
      }
      if (f1 > sc) {
        int p = atomicAdd(&s_sure, 1);
        if (p < TOPK) { fIdx[p] = ib + 1; fVal[p] = f1 > 0.f ? f1 : 0.f; }
      } else if (f1 >= al) {
        int p = atomicAdd(&s_amb, 1);
        if (p < MAXC) idxs[p] = ib + 1;
      }
    }
  }
  __syncthreads();
  const int S = s_sure < TOPK ? s_sure : TOPK;
  const int cnt = s_amb < MAXC ? s_amb : MAXC;
  for (int c = tid; c < cnt; c += 256) bes[c] = b_enc[idxs[c]];
  __syncthreads();

  // candidate-invariant x slice -> fp32 registers (last read of xs)
  float xr[16];
#pragma unroll
  for (int ch = 0; ch < 4; ++ch)
#pragma unroll
    for (int j = 0; j < 4; ++j)
      xr[ch * 4 + j] = xs[ch * 256 + lane * 4 + j];

#define ISSUE_ROW(c_, b_)                                                  \
  {                                                                        \
    int cc_ = (c_) < cnt ? (c_) : 0;                                       \
    const float* src_ = Wenc + (size_t)idxs[cc_] * F_ + lane * 4;          \
    float* dst_ = &wbuf[wave][(b_)][lane * 4];                             \
    async16(src_ + 0, dst_ + 0);                                           \
    async16(src_ + 256, dst_ + 256);                                       \
    async16(src_ + 512, dst_ + 512);                                       \
    async16(src_ + 768, dst_ + 768);                                       \
  }

  const int nIter = (cnt - wave + 3) / 4;
  ISSUE_ROW(wave, 0);
  ISSUE_ROW(wave + 4, 1);

  for (int i = 0; i < nIter; ++i) {
    const int c = wave + i * 4;
    const int bsel = i & 1;
    asm volatile("s_waitcnt vmcnt(4)" ::: "memory");
    __builtin_amdgcn_sched_barrier(0);

    const float4* wr = (const float4*)wbuf[wave][bsel];
    double s = 0.0;
#pragma unroll
    for (int ch = 0; ch < 4; ++ch) {
      float4 wv = wr[ch * 64 + lane];
      s = fma((double)xr[ch * 4 + 0], (double)wv.x, s);
      s = fma((double)xr[ch * 4 + 1], (double)wv.y, s);
      s = fma((double)xr[ch * 4 + 2], (double)wv.z, s);
      s = fma((double)xr[ch * 4 + 3], (double)wv.w, s);
    }
    __builtin_amdgcn_sched_barrier(0);
    ISSUE_ROW(wave + (i + 2) * 4, bsel);

#pragma unroll
    for (int off = 32; off > 0; off >>= 1) s += __shfl_xor(s, off);
    if (lane == 0 && c < cnt) vals[c] = s + (double)bes[c];
  }
#undef ISSUE_ROW
  __syncthreads();

  // exact ranking among ambiguous; top (TOPK - S) win slots S..TOPK-1
  const int Kp = TOPK - S;
  for (int c = tid; c < cnt; c += 256) {
    const double v = vals[c];
    const int h = idxs[c];
    int rank = 0;
    for (int o = 0; o < cnt; ++o) {
      double vo = vals[o];
      rank += (vo > v) || (vo == v && idxs[o] < h);  // jax tie-break
    }
    if (rank < Kp) {
      float fv = v > 0.0 ? (float)v : 0.0f;
      fIdx[S + rank] = h;
      fVal[S + rank] = fv;
    }
  }
  __syncthreads();  // fIdx/fVal final

  // export list (k_zs consumes rows >= 2048); scatter f for first-half rows
  if (tid < TOPK) {
    decIdx[row * TOPK + tid] = fIdx[tid];
    decVal[row * TOPK + tid] = fVal[tid];
    if (row < B_ / 2) frow[fIdx[tid] & (H_ - 1)] = fVal[tid];
  }

  // ---- decode phase: xhat[row,:] = sum_j fVal[j] * WdecT[fIdx[j],:] + b_dec
  // threads 0-127 even j / 128-255 odd j; 8 owned cols each; 16B loads.
  const int cb = (tid & 127) * 8;
  const int par = tid >> 7;
  float a[8] = {0.f, 0.f, 0.f, 0.f, 0.f, 0.f, 0.f, 0.f};
#pragma unroll 8
  for (int j2 = 0; j2 < TOPK / 2; ++j2) {
    const int j = j2 * 2 + par;
    const float v = fVal[j];
    const u16x8 w = *(const u16x8*)(WdecT + (size_t)(fIdx[j] & (H_ - 1)) * F_ + cb);
#pragma unroll
    for (int k = 0; k < 8; ++k) a[k] += v * bf2f(w[k]);
  }
  if (par) {
#pragma unroll
    for (int k = 0; k < 8; ++k) xs[cb + k] = a[k];  // xs reused as partials
  }
  __syncthreads();
  if (!par) {
    float4 bd0 = *(const float4*)(b_dec + cb);
    float4 bd1 = *(const float4*)(b_dec + cb + 4);
    float4 o0, o1;
    o0.x = a[0] + xs[cb + 0] + bd0.x;
    o0.y = a[1] + xs[cb + 1] + bd0.y;
    o0.z = a[2] + xs[cb + 2] + bd0.z;
    o0.w = a[3] + xs[cb + 3] + bd0.w;
    o1.x = a[4] + xs[cb + 4] + bd1.x;
    o1.y = a[5] + xs[cb + 5] + bd1.y;
    o1.z = a[6] + xs[cb + 6] + bd1.z;
    o1.w = a[7] + xs[cb + 7] + bd1.w;
    float* xp = xhat + (size_t)row * F_ + cb;
    *(float4*)xp = o0;
    *(float4*)(xp + 4) = o1;
  }
}

// ---- K3: second-half zero + scatter (af16 fully dead once selrefdec done) ----
__global__ __launch_bounds__(256) void k_zs(const int* __restrict__ decIdx,
                                            const float* __restrict__ decVal,
                                            float* __restrict__ f) {
  const int row = B_ / 2 + blockIdx.x, tid = threadIdx.x;
  float* frow = f + (size_t)row * H_;
  const f32x4 z4 = {0.f, 0.f, 0.f, 0.f};
  for (int i = tid; i < H_ / 4; i += 256)
    __builtin_nontemporal_store(z4, (f32x4*)frow + i);
  __syncthreads();  // drains vmcnt: zeros committed before scatter
  if (tid < TOPK)
    frow[decIdx[row * TOPK + tid] & (H_ - 1)] = decVal[row * TOPK + tid];
}

extern "C" void kernel_launch(void* const* d_in, const int* in_sizes, int n_in,
                              void* d_out, int out_size, void* d_ws, size_t ws_size,
                              hipStream_t stream) {
  const float* x    = (const float*)d_in[0];
  const float* Wenc = (const float*)d_in[1];
  const float* benc = (const float*)d_in[2];
  const float* Wdec = (const float*)d_in[3];
  const float* bdec = (const float*)d_in[4];

  float* out  = (float*)d_out;
  float* f    = out;                       // [4096][16384] fp32
  float* xhat = out + (size_t)B_ * H_;     // [4096][1024]
  // fp16 'a' lives in the upper half of the f region (fully consumed by
  // k_selrefdec before k_zs zero-fills that half) — no ws growth.
  u16* af16 = (u16*)(f + (size_t)B_ * H_ / 2);  // 128 MB

  char* ws = (char*)d_ws;
  u16*  xbar    = (u16*)ws;                             // 8 MB (fp16)
  u16*  wencb   = (u16*)(ws + (size_t)(8)  * 1048576);  // 32 MB (fp16)
  u16*  wdecT   = (u16*)(ws + (size_t)(40) * 1048576);  // 32 MB (bf16)
  int*  decIdx  = (int*)(ws + (size_t)(76) * 1048576);  // 1 MB
  float* decVal = (float*)(ws + (size_t)(77) * 1048576);// 1 MB

  k_xbar<<<B_ * F_ / 1024, 256, 0, stream>>>(x, bdec, xbar);
  k_cast<<<H_ * F_ / 1024, 256, 0, stream>>>(Wenc, wencb);
  k_transpose<<<dim3(H_ / 32, F_ / 32), 256, 0, stream>>>(Wdec, wdecT);
  k_gemm<<<dim3(H_ / 128, B_ / 128), 256, 0, stream>>>(xbar, wencb, benc, af16);
  k_selrefdec<<<B_, 256, 0, stream>>>(af16, x, bdec, Wenc, benc, wdecT,
                                      f, xhat, decIdx, decVal);
  k_zs<<<B_ / 2, 256, 0, stream>>>(decIdx, decVal, f);
}

// Round 7
// 707.864 us; speedup vs baseline: 1.0565x; 1.0293x over previous
//
#include <hip/hip_runtime.h>
#include <cstdint>

#define B_ 4096
#define F_ 1024
#define H_ 16384
#define TOPK 64
#define MAXC 192
// 2E: twice the bound on |a_fp16_stored - a_ref|.
// fp16-GEMM error <= 0.0031 (bf16's proven 0.025 scaled by 2^-3) +
// fp16 storage rounding <= 0.002  => E=0.010 gives ~2x headroom.
#define TWOE 0.020f

typedef unsigned short u16;
typedef __attribute__((ext_vector_type(8))) _Float16 f16x8;
typedef __attribute__((ext_vector_type(8))) unsigned short u16x8;
typedef __attribute__((ext_vector_type(4))) float f32x4;

__device__ __forceinline__ u16 f2bf(float f) {
  union { float f; uint32_t u; } v; v.f = f;
  uint32_t u = v.u;
  uint32_t r = u + 0x7FFFu + ((u >> 16) & 1u);
  return (u16)(r >> 16);
}
__device__ __forceinline__ float bf2f(u16 h) {
  union { uint32_t u; float f; } v; v.u = ((uint32_t)h) << 16; return v.f;
}
__device__ __forceinline__ u16 f2h(float f) {
  union { _Float16 h; u16 u; } v; v.h = (_Float16)f; return v.u;
}
__device__ __forceinline__ float h2f(u16 h) {
  union { _Float16 h; u16 u; } v; v.u = h; return (float)v.h;
}
// packed pair of fp16: zero any negative half (key space: monotone for >=0)
__device__ __forceinline__ uint32_t key2(uint32_t v) {
  uint32_t s = (v >> 15) & 0x00010001u;
  return v & ~(s * 0xFFFFu);
}

__device__ __forceinline__ void async16(const void* g, void* l) {
  __builtin_amdgcn_global_load_lds(
      reinterpret_cast<const __attribute__((address_space(1))) uint32_t*>(
          reinterpret_cast<uintptr_t>(g)),
      reinterpret_cast<__attribute__((address_space(3))) uint32_t*>(
          reinterpret_cast<uintptr_t>(l)),
      16, 0, 0);
}

// ---- K0a: xbar = fp16(x - b_dec) ----
__global__ __launch_bounds__(256) void k_xbar(const float* __restrict__ x,
                                              const float* __restrict__ b_dec,
                                              u16* __restrict__ xbar) {
  int i = blockIdx.x * 256 + threadIdx.x;
  int base = i * 4;
  int col = base & (F_ - 1);
  float4 xv = *(const float4*)(x + base);
  float4 bv = *(const float4*)(b_dec + col);
  ushort4 o;
  o.x = f2h(xv.x - bv.x); o.y = f2h(xv.y - bv.y);
  o.z = f2h(xv.z - bv.z); o.w = f2h(xv.w - bv.w);
  *(ushort4*)(xbar + base) = o;
}

// ---- K0b: fp16 cast of W_enc ----
__global__ __launch_bounds__(256) void k_cast(const float* __restrict__ src,
                                              u16* __restrict__ dst) {
  size_t base = (size_t)(blockIdx.x * 256 + threadIdx.x) * 4;
  float4 v = *(const float4*)(src + base);
  ushort4 o; o.x = f2h(v.x); o.y = f2h(v.y); o.z = f2h(v.z); o.w = f2h(v.w);
  *(ushort4*)(dst + base) = o;
}

// ---- K0c: W_dec [F,H] fp32 -> W_decT [H,F] bf16 (decode path unchanged) ----
__global__ __launch_bounds__(256) void k_transpose(const float* __restrict__ Wdec,
                                                   u16* __restrict__ WdecT) {
  __shared__ float tile[32][33];
  int hb = blockIdx.x * 32, fb = blockIdx.y * 32;
  int tx = threadIdx.x & 31, ty = threadIdx.x >> 5;  // ty 0..7
#pragma unroll
  for (int i = 0; i < 32; i += 8)
    tile[ty + i][tx] = Wdec[(size_t)(fb + ty + i) * H_ + hb + tx];
  __syncthreads();
#pragma unroll
  for (int i = 0; i < 32; i += 8)
    WdecT[(size_t)(hb + ty + i) * F_ + fb + tx] = f2bf(tile[tx][ty + i]);
}

// ---- K1: fp16 MFMA GEMM, 2-phase dbuf with FULLY-UNROLLED K-loop.
// Round-6 PMC showed VALUBusy 58% (vs 16% in the unrolled round-4 loop):
// `#pragma unroll 1` forced runtime (t+1)*32 staging offsets = 64-bit addr
// math per async16 every tile, rivaling the 16 MFMAs' matrix-pipe cycles.
// Full unroll makes buffer parity (t&1) and the stage offset ((t+1)*64 B,
// max 1984 B -> fits the 13-bit signed imm) compile-time: zero per-tile
// address VALU + still one barrier per tile. Numerics bit-identical.
__device__ __forceinline__ void gemm_step(const u16* __restrict__ bA,
                                          const u16* __restrict__ bB,
                                          int aoff, int boff, int kcp,
                                          f32x4 (&acc)[4][4]) {
  f16x8 av[4], bv[4];
#pragma unroll
  for (int i = 0; i < 4; ++i)
    av[i] = *(const f16x8*)&bA[(aoff + i * 16) * 32 + kcp];
#pragma unroll
  for (int j = 0; j < 4; ++j)
    bv[j] = *(const f16x8*)&bB[(boff + j * 16) * 32 + kcp];
#pragma unroll
  for (int i = 0; i < 4; ++i)
#pragma unroll
    for (int j = 0; j < 4; ++j)
      acc[i][j] = __builtin_amdgcn_mfma_f32_16x16x32_f16(av[i], bv[j], acc[i][j], 0, 0, 0);
}

__global__ __launch_bounds__(256) void k_gemm(const u16* __restrict__ A,
                                              const u16* __restrict__ Bm,
                                              const float* __restrict__ b_enc,
                                              u16* __restrict__ Cf16) {
  __shared__ u16 lA[2][128 * 32];
  __shared__ u16 lB[2][128 * 32];
  const int tid = threadIdx.x;
  const int lane = tid & 63, wave = tid >> 6;
  const int wm = wave >> 1, wn = wave & 1;
  const int bx = blockIdx.x, by = blockIdx.y;

  const int kcs = (tid & 3) ^ ((tid >> 3) & 3);  // swizzled source chunk
  const u16* gA0 = A + (size_t)(by * 128 + (tid >> 2)) * F_ + kcs * 8;
  const u16* gA1 = gA0 + 64 * F_;
  const u16* gB0 = Bm + (size_t)(bx * 128 + (tid >> 2)) * F_ + kcs * 8;
  const u16* gB1 = gB0 + 64 * F_;

#define STAGE(b_, k0_)                          \
  {                                             \
    async16(gA0 + (k0_), &lA[b_][tid * 8]);     \
    async16(gA1 + (k0_), &lA[b_][tid * 8 + 2048]); \
    async16(gB0 + (k0_), &lB[b_][tid * 8]);     \
    async16(gB1 + (k0_), &lB[b_][tid * 8 + 2048]); \
  }

  f32x4 acc[4][4] = {};
  const int lm = lane & 15;
  const int kcp = (((lane >> 4) ^ ((lm >> 1) & 3))) * 8;  // swizzled read offset
  const int aoff = wm * 64 + lm, boff = wn * 64 + lm;

  STAGE(0, 0);
  __syncthreads();  // vmcnt(0) drain: tile 0 resident
  // tiles 0..30: stage tile t+1 into buf (t+1)&1, compute tile t from buf t&1.
  // Full unroll: all buffer indices and stage offsets are compile-time.
#pragma unroll
  for (int t = 0; t < 31; ++t) {
    if ((t & 1) == 0) {
      STAGE(1, (t + 1) * 32);
      gemm_step(lA[0], lB[0], aoff, boff, kcp, acc);
    } else {
      STAGE(0, (t + 1) * 32);
      gemm_step(lA[1], lB[1], aoff, boff, kcp, acc);
    }
    __syncthreads();  // drains stage; swap safe
  }
  gemm_step(lA[1], lB[1], aoff, boff, kcp, acc);  // tile 31 (buf 1)
#undef STAGE

#pragma unroll
  for (int i = 0; i < 4; ++i) {
    int rowg = by * 128 + wm * 64 + i * 16 + (lane >> 4) * 4;
#pragma unroll
    for (int j = 0; j < 4; ++j) {
      int colg = bx * 128 + wn * 64 + j * 16 + lm;
      float be = b_enc[colg];
      u16* cp = Cf16 + (size_t)rowg * H_ + colg;
#pragma unroll
      for (int r = 0; r < 4; ++r)
        cp[(size_t)r * H_] = f2h(acc[i][j][r] + be);
    }
  }
}

// ---- K2: fused select + refine + decode (unchanged from round 6) ----
__global__ __launch_bounds__(256) void k_selrefdec(const u16* __restrict__ af16,
                                                   const float* __restrict__ x,
                                                   const float* __restrict__ b_dec,
                                                   const float* __restrict__ Wenc,
                                                   const float* __restrict__ b_enc,
                                                   const u16* __restrict__ WdecT,
                                                   float* __restrict__ f,
                                                   float* __restrict__ xhat,
                                                   int* __restrict__ decIdx,
                                                   float* __restrict__ decVal) {
  const int row = blockIdx.x, tid = threadIdx.x;
  const int lane = tid & 63, wave = tid >> 6;
  __shared__ float wbuf[4][2][F_];  // 32 KB refine gather buffers
  __shared__ float xs[F_];          // 4 KB; reused as decode parity partials
  __shared__ double vals[MAXC];     // 1.5 KB
  __shared__ float bes[MAXC];
  __shared__ int idxs[MAXC];
  __shared__ int fIdx[TOPK];        // final top-64 (LDS-resident for decode)
  __shared__ float fVal[TOPK];
  __shared__ int s_cnt8[2][4];
  __shared__ int s_sure, s_amb;

  if (tid == 0) { s_sure = 0; s_amb = 0; idxs[0] = 0; }
  if (tid < TOPK) { fIdx[tid] = 0; fVal[tid] = 0.f; }
  for (int k = tid; k < F_; k += 256)
    xs[k] = x[(size_t)row * F_ + k] - b_dec[k];

  float* frow = f + (size_t)row * H_;
  if (row < B_ / 2) {  // first half: zero own row now (hidden under search)
    const f32x4 z4 = {0.f, 0.f, 0.f, 0.f};
    for (int i = tid; i < H_ / 4; i += 256)
      __builtin_nontemporal_store(z4, (f32x4*)frow + i);
  }

  // row -> registers as sort keys (64 halfs = 32 packed u32 per thread)
  uint32_t pr[32];
  {
    const uint4* arow16 = (const uint4*)(af16 + (size_t)row * H_);
#pragma unroll
    for (int j = 0; j < 8; ++j) {
      uint4 v = arow16[tid + 256 * j];
      pr[j * 4 + 0] = key2(v.x);
      pr[j * 4 + 1] = key2(v.y);
      pr[j * 4 + 2] = key2(v.z);
      pr[j * 4 + 3] = key2(v.w);
    }
  }

  // binary search largest t with count(key >= t) >= TOPK  ->  t = stored v64
  uint32_t lo = 0, hi = 0x7C00;
  int it = 0;
  while (hi - lo > 1) {
    const uint32_t mid = (lo + hi) >> 1;
    int c = 0;
#pragma unroll
    for (int r = 0; r < 32; ++r) {
      c += ((pr[r] & 0xFFFFu) >= mid);
      c += ((pr[r] >> 16) >= mid);
    }
#pragma unroll
    for (int off = 32; off > 0; off >>= 1) c += __shfl_xor(c, off);
    if (lane == 0) s_cnt8[it & 1][wave] = c;
    __syncthreads();
    const int* scp = s_cnt8[it & 1];
    const int tot = scp[0] + scp[1] + scp[2] + scp[3];
    if (tot >= TOPK) lo = mid; else hi = mid;
    ++it;  // double-buffered slot: safe with one barrier per iter
  }
  const float v64f = h2f((u16)lo);
  const float sc = v64f + TWOE;  // stored >  sc: surely in top-64
  const float al = v64f - TWOE;  // stored <  al: surely out

#pragma unroll
  for (int j = 0; j < 8; ++j) {
#pragma unroll
    for (int w = 0; w < 4; ++w) {
      const uint32_t v = pr[j * 4 + w];
      const int ib = (tid + 256 * j) * 8 + w * 2;
      const float f0 = h2f((u16)(v & 0xFFFFu));
      const float f1 = h2f((u16)(v >> 16));
      if (f0 > sc) {
        int p = atomicAdd(&s_sure, 1);
        if (p < TOPK) { fIdx[p] = ib; fVal[p] = f0 > 0.f ? f0 : 0.f; }
      } else if (f0 >= al) {
        int p = atomicAdd(&s_amb, 1);
        if (p < MAXC) idxs[p] = ib;
      }
      if (f1 > sc) {
        int p = atomicAdd(&s_sure, 1);
        if (p < TOPK) { fIdx[p] = ib + 1; fVal[p] = f1 > 0.f ? f1 : 0.f; }
      } else if (f1 >= al) {
        int p = atomicAdd(&s_amb, 1);
        if (p < MAXC) idxs[p] = ib + 1;
      }
    }
  }
  __syncthreads();
  const int S = s_sure < TOPK ? s_sure : TOPK;
  const int cnt = s_amb < MAXC ? s_amb : MAXC;
  for (int c = tid; c < cnt; c += 256) bes[c] = b_enc[idxs[c]];
  __syncthreads();

  // candidate-invariant x slice -> fp32 registers (last read of xs)
  float xr[16];
#pragma unroll
  for (int ch = 0; ch < 4; ++ch)
#pragma unroll
    for (int j = 0; j < 4; ++j)
      xr[ch * 4 + j] = xs[ch * 256 + lane * 4 + j];

#define ISSUE_ROW(c_, b_)                                                  \
  {                                                                        \
    int cc_ = (c_) < cnt ? (c_) : 0;                                       \
    const float* src_ = Wenc + (size_t)idxs[cc_] * F_ + lane * 4;          \
    float* dst_ = &wbuf[wave][(b_)][lane * 4];                             \
    async16(src_ + 0, dst_ + 0);                                           \
    async16(src_ + 256, dst_ + 256);                                       \
    async16(src_ + 512, dst_ + 512);                                       \
    async16(src_ + 768, dst_ + 768);                                       \
  }

  const int nIter = (cnt - wave + 3) / 4;
  ISSUE_ROW(wave, 0);
  ISSUE_ROW(wave + 4, 1);

  for (int i = 0; i < nIter; ++i) {
    const int c = wave + i * 4;
    const int bsel = i & 1;
    asm volatile("s_waitcnt vmcnt(4)" ::: "memory");
    __builtin_amdgcn_sched_barrier(0);

    const float4* wr = (const float4*)wbuf[wave][bsel];
    double s = 0.0;
#pragma unroll
    for (int ch = 0; ch < 4; ++ch) {
      float4 wv = wr[ch * 64 + lane];
      s = fma((double)xr[ch * 4 + 0], (double)wv.x, s);
      s = fma((double)xr[ch * 4 + 1], (double)wv.y, s);
      s = fma((double)xr[ch * 4 + 2], (double)wv.z, s);
      s = fma((double)xr[ch * 4 + 3], (double)wv.w, s);
    }
    __builtin_amdgcn_sched_barrier(0);
    ISSUE_ROW(wave + (i + 2) * 4, bsel);

#pragma unroll
    for (int off = 32; off > 0; off >>= 1) s += __shfl_xor(s, off);
    if (lane == 0 && c < cnt) vals[c] = s + (double)bes[c];
  }
#undef ISSUE_ROW
  __syncthreads();

  // exact ranking among ambiguous; top (TOPK - S) win slots S..TOPK-1
  const int Kp = TOPK - S;
  for (int c = tid; c < cnt; c += 256) {
    const double v = vals[c];
    const int h = idxs[c];
    int rank = 0;
    for (int o = 0; o < cnt; ++o) {
      double vo = vals[o];
      rank += (vo > v) || (vo == v && idxs[o] < h);  // jax tie-break
    }
    if (rank < Kp) {
      float fv = v > 0.0 ? (float)v : 0.0f;
      fIdx[S + rank] = h;
      fVal[S + rank] = fv;
    }
  }
  __syncthreads();  // fIdx/fVal final

  // export list (k_zs consumes rows >= 2048); scatter f for first-half rows
  if (tid < TOPK) {
    decIdx[row * TOPK + tid] = fIdx[tid];
    decVal[row * TOPK + tid] = fVal[tid];
    if (row < B_ / 2) frow[fIdx[tid] & (H_ - 1)] = fVal[tid];
  }

  // ---- decode phase: xhat[row,:] = sum_j fVal[j] * WdecT[fIdx[j],:] + b_dec
  const int cb = (tid & 127) * 8;
  const int par = tid >> 7;
  float a[8] = {0.f, 0.f, 0.f, 0.f, 0.f, 0.f, 0.f, 0.f};
#pragma unroll 8
  for (int j2 = 0; j2 < TOPK / 2; ++j2) {
    const int j = j2 * 2 + par;
    const float v = fVal[j];
    const u16x8 w = *(const u16x8*)(WdecT + (size_t)(fIdx[j] & (H_ - 1)) * F_ + cb);
#pragma unroll
    for (int k = 0; k < 8; ++k) a[k] += v * bf2f(w[k]);
  }
  if (par) {
#pragma unroll
    for (int k = 0; k < 8; ++k) xs[cb + k] = a[k];  // xs reused as partials
  }
  __syncthreads();
  if (!par) {
    float4 bd0 = *(const float4*)(b_dec + cb);
    float4 bd1 = *(const float4*)(b_dec + cb + 4);
    float4 o0, o1;
    o0.x = a[0] + xs[cb + 0] + bd0.x;
    o0.y = a[1] + xs[cb + 1] + bd0.y;
    o0.z = a[2] + xs[cb + 2] + bd0.z;
    o0.w = a[3] + xs[cb + 3] + bd0.w;
    o1.x = a[4] + xs[cb + 4] + bd1.x;
    o1.y = a[5] + xs[cb + 5] + bd1.y;
    o1.z = a[6] + xs[cb + 6] + bd1.z;
    o1.w = a[7] + xs[cb + 7] + bd1.w;
    float* xp = xhat + (size_t)row * F_ + cb;
    *(float4*)xp = o0;
    *(float4*)(xp + 4) = o1;
  }
}

// ---- K3: second-half zero + scatter (af16 fully dead once selrefdec done) ----
__global__ __launch_bounds__(256) void k_zs(const int* __restrict__ decIdx,
                                            const float* __restrict__ decVal,
                                            float* __restrict__ f) {
  const int row = B_ / 2 + blockIdx.x, tid = threadIdx.x;
  float* frow = f + (size_t)row * H_;
  const f32x4 z4 = {0.f, 0.f, 0.f, 0.f};
  for (int i = tid; i < H_ / 4; i += 256)
    __builtin_nontemporal_store(z4, (f32x4*)frow + i);
  __syncthreads();  // drains vmcnt: zeros committed before scatter
  if (tid < TOPK)
    frow[decIdx[row * TOPK + tid] & (H_ - 1)] = decVal[row * TOPK + tid];
}

extern "C" void kernel_launch(void* const* d_in, const int* in_sizes, int n_in,
                              void* d_out, int out_size, void* d_ws, size_t ws_size,
                              hipStream_t stream) {
  const float* x    = (const float*)d_in[0];
  const float* Wenc = (const float*)d_in[1];
  const float* benc = (const float*)d_in[2];
  const float* Wdec = (const float*)d_in[3];
  const float* bdec = (const float*)d_in[4];

  float* out  = (float*)d_out;
  float* f    = out;                       // [4096][16384] fp32
  float* xhat = out + (size_t)B_ * H_;     // [4096][1024]
  // fp16 'a' lives in the upper half of the f region (fully consumed by
  // k_selrefdec before k_zs zero-fills that half) — no ws growth.
  u16* af16 = (u16*)(f + (size_t)B_ * H_ / 2);  // 128 MB

  char* ws = (char*)d_ws;
  u16*  xbar    = (u16*)ws;                             // 8 MB (fp16)
  u16*  wencb   = (u16*)(ws + (size_t)(8)  * 1048576);  // 32 MB (fp16)
  u16*  wdecT   = (u16*)(ws + (size_t)(40) * 1048576);  // 32 MB (bf16)
  int*  decIdx  = (int*)(ws + (size_t)(76) * 1048576);  // 1 MB
  float* decVal = (float*)(ws + (size_t)(77) * 1048576);// 1 MB

  k_xbar<<<B_ * F_ / 1024, 256, 0, stream>>>(x, bdec, xbar);
  k_cast<<<H_ * F_ / 1024, 256, 0, stream>>>(Wenc, wencb);
  k_transpose<<<dim3(H_ / 32, F_ / 32), 256, 0, stream>>>(Wdec, wdecT);
  k_gemm<<<dim3(H_ / 128, B_ / 128), 256, 0, stream>>>(xbar, wencb, benc, af16);
  k_selrefdec<<<B_, 256, 0, stream>>>(af16, x, bdec, Wenc, benc, wdecT,
                                      f, xhat, decIdx, decVal);
  k_zs<<<B_ / 2, 256, 0, stream>>>(decIdx, decVal, f);
}

// Round 8
// 704.932 us; speedup vs baseline: 1.0609x; 1.0042x over previous
//
#include <hip/hip_runtime.h>
#include <cstdint>

#define B_ 4096
#define F_ 1024
#define H_ 16384
#define TOPK 64
#define MAXC 192
// 2E: twice the bound on |a_fp16_stored - a_ref| AT THE SELECTION BOUNDARY
// (|a|~1.5): fp16-GEMM err <= ~0.004 + fp16 storage rounding <= 0.001.
// E=0.010 gives ~2x headroom. (absmax 0.0156 comes from LARGE a values where
// storage ulp is bigger; boundary-region error is what classification needs.)
#define TWOE 0.020f

#if defined(__has_builtin)
#if __has_builtin(__builtin_amdgcn_fdot2)
#define HAVE_FDOT2 1
#endif
#endif

typedef unsigned short u16;
typedef __attribute__((ext_vector_type(8))) _Float16 f16x8;
typedef __attribute__((ext_vector_type(2))) _Float16 h16x2;
typedef __attribute__((ext_vector_type(8))) unsigned short u16x8;
typedef __attribute__((ext_vector_type(4))) float f32x4;

__device__ __forceinline__ u16 f2bf(float f) {
  union { float f; uint32_t u; } v; v.f = f;
  uint32_t u = v.u;
  uint32_t r = u + 0x7FFFu + ((u >> 16) & 1u);
  return (u16)(r >> 16);
}
__device__ __forceinline__ float bf2f(u16 h) {
  union { uint32_t u; float f; } v; v.u = ((uint32_t)h) << 16; return v.f;
}
__device__ __forceinline__ u16 f2h(float f) {
  union { _Float16 h; u16 u; } v; v.h = (_Float16)f; return v.u;
}
__device__ __forceinline__ float h2f(u16 h) {
  union { _Float16 h; u16 u; } v; v.u = h; return (float)v.h;
}
// packed pair of fp16: zero any negative half (key space: monotone for >=0)
__device__ __forceinline__ uint32_t key2(uint32_t v) {
  uint32_t s = (v >> 15) & 0x00010001u;
  return v & ~(s * 0xFFFFu);
}

__device__ __forceinline__ void async16(const void* g, void* l) {
  __builtin_amdgcn_global_load_lds(
      reinterpret_cast<const __attribute__((address_space(1))) uint32_t*>(
          reinterpret_cast<uintptr_t>(g)),
      reinterpret_cast<__attribute__((address_space(3))) uint32_t*>(
          reinterpret_cast<uintptr_t>(l)),
      16, 0, 0);
}

// ---- K0: merged prep (xbar | cast | transpose) — one launch, one BW wave.
// blocks [0,4096): xbar = fp16(x - b_dec)
// blocks [4096,20480): wencb = fp16(Wenc)
// blocks [20480,36864): wdecT = fp16(Wdec^T)   (fp16 now: feeds fdot2 decode,
//                       strictly better mantissa than bf16)
__global__ __launch_bounds__(256) void k_prep(const float* __restrict__ x,
                                              const float* __restrict__ b_dec,
                                              const float* __restrict__ Wenc,
                                              const float* __restrict__ Wdec,
                                              u16* __restrict__ xbar,
                                              u16* __restrict__ wencb,
                                              u16* __restrict__ wdecT) {
  __shared__ float tile[32][33];
  const int b = blockIdx.x, tid = threadIdx.x;
  if (b < 4096) {  // xbar
    int i = b * 256 + tid;
    int base = i * 4;
    int col = base & (F_ - 1);
    float4 xv = *(const float4*)(x + base);
    float4 bv = *(const float4*)(b_dec + col);
    ushort4 o;
    o.x = f2h(xv.x - bv.x); o.y = f2h(xv.y - bv.y);
    o.z = f2h(xv.z - bv.z); o.w = f2h(xv.w - bv.w);
    *(ushort4*)(xbar + base) = o;
  } else if (b < 20480) {  // cast W_enc
    size_t base = ((size_t)(b - 4096) * 256 + tid) * 4;
    float4 v = *(const float4*)(Wenc + base);
    ushort4 o; o.x = f2h(v.x); o.y = f2h(v.y); o.z = f2h(v.z); o.w = f2h(v.w);
    *(ushort4*)(wencb + base) = o;
  } else {  // transpose W_dec -> fp16 W_decT
    const int t = b - 20480;
    const int hb = (t & 511) * 32, fb = (t >> 9) * 32;
    const int tx = tid & 31, ty = tid >> 5;  // ty 0..7
#pragma unroll
    for (int i = 0; i < 32; i += 8)
      tile[ty + i][tx] = Wdec[(size_t)(fb + ty + i) * H_ + hb + tx];
    __syncthreads();
#pragma unroll
    for (int i = 0; i < 32; i += 8)
      wdecT[(size_t)(hb + ty + i) * F_ + fb + tx] = f2h(tile[tx][ty + i]);
  }
}

// ---- K1: fp16 MFMA GEMM, 2-phase dbuf, fully-unrolled K-loop (round-7,
// unchanged: compile-time buffer parity + imm stage offsets; 1 barrier/tile).
__device__ __forceinline__ void gemm_step(const u16* __restrict__ bA,
                                          const u16* __restrict__ bB,
                                          int aoff, int boff, int kcp,
                                          f32x4 (&acc)[4][4]) {
  f16x8 av[4], bv[4];
#pragma unroll
  for (int i = 0; i < 4; ++i)
    av[i] = *(const f16x8*)&bA[(aoff + i * 16) * 32 + kcp];
#pragma unroll
  for (int j = 0; j < 4; ++j)
    bv[j] = *(const f16x8*)&bB[(boff + j * 16) * 32 + kcp];
#pragma unroll
  for (int i = 0; i < 4; ++i)
#pragma unroll
    for (int j = 0; j < 4; ++j)
      acc[i][j] = __builtin_amdgcn_mfma_f32_16x16x32_f16(av[i], bv[j], acc[i][j], 0, 0, 0);
}

__global__ __launch_bounds__(256) void k_gemm(const u16* __restrict__ A,
                                              const u16* __restrict__ Bm,
                                              const float* __restrict__ b_enc,
                                              u16* __restrict__ Cf16) {
  __shared__ u16 lA[2][128 * 32];
  __shared__ u16 lB[2][128 * 32];
  const int tid = threadIdx.x;
  const int lane = tid & 63, wave = tid >> 6;
  const int wm = wave >> 1, wn = wave & 1;
  const int bx = blockIdx.x, by = blockIdx.y;

  const int kcs = (tid & 3) ^ ((tid >> 3) & 3);  // swizzled source chunk
  const u16* gA0 = A + (size_t)(by * 128 + (tid >> 2)) * F_ + kcs * 8;
  const u16* gA1 = gA0 + 64 * F_;
  const u16* gB0 = Bm + (size_t)(bx * 128 + (tid >> 2)) * F_ + kcs * 8;
  const u16* gB1 = gB0 + 64 * F_;

#define STAGE(b_, k0_)                          \
  {                                             \
    async16(gA0 + (k0_), &lA[b_][tid * 8]);     \
    async16(gA1 + (k0_), &lA[b_][tid * 8 + 2048]); \
    async16(gB0 + (k0_), &lB[b_][tid * 8]);     \
    async16(gB1 + (k0_), &lB[b_][tid * 8 + 2048]); \
  }

  f32x4 acc[4][4] = {};
  const int lm = lane & 15;
  const int kcp = (((lane >> 4) ^ ((lm >> 1) & 3))) * 8;  // swizzled read offset
  const int aoff = wm * 64 + lm, boff = wn * 64 + lm;

  STAGE(0, 0);
  __syncthreads();  // vmcnt(0) drain: tile 0 resident
#pragma unroll
  for (int t = 0; t < 31; ++t) {
    if ((t & 1) == 0) {
      STAGE(1, (t + 1) * 32);
      gemm_step(lA[0], lB[0], aoff, boff, kcp, acc);
    } else {
      STAGE(0, (t + 1) * 32);
      gemm_step(lA[1], lB[1], aoff, boff, kcp, acc);
    }
    __syncthreads();  // drains stage; swap safe
  }
  gemm_step(lA[1], lB[1], aoff, boff, kcp, acc);  // tile 31 (buf 1)
#undef STAGE

#pragma unroll
  for (int i = 0; i < 4; ++i) {
    int rowg = by * 128 + wm * 64 + i * 16 + (lane >> 4) * 4;
#pragma unroll
    for (int j = 0; j < 4; ++j) {
      int colg = bx * 128 + wn * 64 + j * 16 + lm;
      float be = b_enc[colg];
      u16* cp = Cf16 + (size_t)rowg * H_ + colg;
#pragma unroll
      for (int r = 0; r < 4; ++r)
        cp[(size_t)r * H_] = f2h(acc[i][j][r] + be);
    }
  }
}

// ---- K2: fused select + refine + decode.
// Round-8 VALU trims (search was ~50% of inst/wave per r7 accounting):
//  * search early-stop at hi-lo<=8 (12 iters, was 15); sc/al from the
//    bracketing keys keep both cuts conservative (v64key in [lo,hi)).
//  * classify in integer key domain (no cvt per value; half-ulp rounding
//    slack of f2h(sc)/f2h(al) is << the E headroom at the boundary).
//  * decode pairs two j's per fdot2 with v_perm packing (fp16 WdecT).
__global__ __launch_bounds__(256) void k_selrefdec(const u16* __restrict__ af16,
                                                   const float* __restrict__ x,
                                                   const float* __restrict__ b_dec,
                                                   const float* __restrict__ Wenc,
                                                   const float* __restrict__ b_enc,
                                                   const u16* __restrict__ WdecT,
                                                   float* __restrict__ f,
                                                   float* __restrict__ xhat,
                                                   int* __restrict__ decIdx,
                                                   float* __restrict__ decVal) {
  const int row = blockIdx.x, tid = threadIdx.x;
  const int lane = tid & 63, wave = tid >> 6;
  __shared__ float wbuf[4][2][F_];  // 32 KB refine gather buffers
  __shared__ float xs[F_];          // 4 KB; reused as decode parity partials
  __shared__ double vals[MAXC];     // 1.5 KB
  __shared__ float bes[MAXC];
  __shared__ int idxs[MAXC];
  __shared__ int fIdx[TOPK];        // final top-64 (LDS-resident for decode)
  __shared__ float fVal[TOPK];
  __shared__ int s_cnt8[2][4];
  __shared__ int s_sure, s_amb;

  if (tid == 0) { s_sure = 0; s_amb = 0; idxs[0] = 0; }
  if (tid < TOPK) { fIdx[tid] = 0; fVal[tid] = 0.f; }
  for (int k = tid; k < F_; k += 256)
    xs[k] = x[(size_t)row * F_ + k] - b_dec[k];

  float* frow = f + (size_t)row * H_;
  if (row < B_ / 2) {  // first half: zero own row now (hidden under search)
    const f32x4 z4 = {0.f, 0.f, 0.f, 0.f};
    for (int i = tid; i < H_ / 4; i += 256)
      __builtin_nontemporal_store(z4, (f32x4*)frow + i);
  }

  // row -> registers as sort keys (64 halfs = 32 packed u32 per thread)
  uint32_t pr[32];
  {
    const uint4* arow16 = (const uint4*)(af16 + (size_t)row * H_);
#pragma unroll
    for (int j = 0; j < 8; ++j) {
      uint4 v = arow16[tid + 256 * j];
      pr[j * 4 + 0] = key2(v.x);
      pr[j * 4 + 1] = key2(v.y);
      pr[j * 4 + 2] = key2(v.z);
      pr[j * 4 + 3] = key2(v.w);
    }
  }

  // binary search, early-stopped: bracket v64key within [lo,hi), hi-lo<=8
  uint32_t lo = 0, hi = 0x7C00;
  int it = 0;
  while (hi - lo > 8) {  // 12 iterations
    const uint32_t mid = (lo + hi) >> 1;
    int c = 0;
#pragma unroll
    for (int r = 0; r < 32; ++r) {
      c += ((pr[r] & 0xFFFFu) >= mid);
      c += ((pr[r] >> 16) >= mid);
    }
#pragma unroll
    for (int off = 32; off > 0; off >>= 1) c += __shfl_xor(c, off);
    if (lane == 0) s_cnt8[it & 1][wave] = c;
    __syncthreads();
    const int* scp = s_cnt8[it & 1];
    const int tot = scp[0] + scp[1] + scp[2] + scp[3];
    if (tot >= TOPK) lo = mid; else hi = mid;
    ++it;  // double-buffered slot: safe with one barrier per iter
  }
  // v64key in [lo,hi): sc/al from the bracket edges stay conservative.
  const float scf = h2f((u16)hi) + TWOE;  // stored > scf: surely in top-64
  const float alf = h2f((u16)lo) - TWOE;  // stored < alf: surely out
  const int ksc = f2h(scf);                       // scf > 0 always
  const int kal = (alf <= 0.f) ? 0 : (int)f2h(alf);

#pragma unroll
  for (int j = 0; j < 8; ++j) {
#pragma unroll
    for (int w = 0; w < 4; ++w) {
      const uint32_t v = pr[j * 4 + w];
      const int ib = (tid + 256 * j) * 8 + w * 2;
      const int k0 = (int)(v & 0xFFFFu), k1 = (int)(v >> 16);
      if (k0 > ksc) {
        int p = atomicAdd(&s_sure, 1);
        if (p < TOPK) { fIdx[p] = ib; fVal[p] = h2f((u16)k0); }  // >sc>0
      } else if (k0 >= kal) {
        int p = atomicAdd(&s_amb, 1);
        if (p < MAXC) idxs[p] = ib;
      }
      if (k1 > ksc) {
        int p = atomicAdd(&s_sure, 1);
        if (p < TOPK) { fIdx[p] = ib + 1; fVal[p] = h2f((u16)k1); }
      } else if (k1 >= kal) {
        int p = atomicAdd(&s_amb, 1);
        if (p < MAXC) idxs[p] = ib + 1;
      }
    }
  }
  __syncthreads();
  const int S = s_sure < TOPK ? s_sure : TOPK;
  const int cnt = s_amb < MAXC ? s_amb : MAXC;
  for (int c = tid; c < cnt; c += 256) bes[c] = b_enc[idxs[c]];
  __syncthreads();

  // candidate-invariant x slice -> fp32 registers (last read of xs as xbar)
  float xr[16];
#pragma unroll
  for (int ch = 0; ch < 4; ++ch)
#pragma unroll
    for (int j = 0; j < 4; ++j)
      xr[ch * 4 + j] = xs[ch * 256 + lane * 4 + j];

#define ISSUE_ROW(c_, b_)                                                  \
  {                                                                        \
    int cc_ = (c_) < cnt ? (c_) : 0;                                       \
    const float* src_ = Wenc + (size_t)idxs[cc_] * F_ + lane * 4;          \
    float* dst_ = &wbuf[wave][(b_)][lane * 4];                             \
    async16(src_ + 0, dst_ + 0);                                           \
    async16(src_ + 256, dst_ + 256);                                       \
    async16(src_ + 512, dst_ + 512);                                       \
    async16(src_ + 768, dst_ + 768);                                       \
  }

  const int nIter = (cnt - wave + 3) / 4;
  ISSUE_ROW(wave, 0);
  ISSUE_ROW(wave + 4, 1);

  for (int i = 0; i < nIter; ++i) {
    const int c = wave + i * 4;
    const int bsel = i & 1;
    asm volatile("s_waitcnt vmcnt(4)" ::: "memory");
    __builtin_amdgcn_sched_barrier(0);

    const float4* wr = (const float4*)wbuf[wave][bsel];
    double s = 0.0;
#pragma unroll
    for (int ch = 0; ch < 4; ++ch) {
      float4 wv = wr[ch * 64 + lane];
      s = fma((double)xr[ch * 4 + 0], (double)wv.x, s);
      s = fma((double)xr[ch * 4 + 1], (double)wv.y, s);
      s = fma((double)xr[ch * 4 + 2], (double)wv.z, s);
      s = fma((double)xr[ch * 4 + 3], (double)wv.w, s);
    }
    __builtin_amdgcn_sched_barrier(0);
    ISSUE_ROW(wave + (i + 2) * 4, bsel);

#pragma unroll
    for (int off = 32; off > 0; off >>= 1) s += __shfl_xor(s, off);
    if (lane == 0 && c < cnt) vals[c] = s + (double)bes[c];
  }
#undef ISSUE_ROW
  __syncthreads();

  // exact ranking among ambiguous; top (TOPK - S) win slots S..TOPK-1
  const int Kp = TOPK - S;
  for (int c = tid; c < cnt; c += 256) {
    const double v = vals[c];
    const int h = idxs[c];
    int rank = 0;
    for (int o = 0; o < cnt; ++o) {
      double vo = vals[o];
      rank += (vo > v) || (vo == v && idxs[o] < h);  // jax tie-break
    }
    if (rank < Kp) {
      float fv = v > 0.0 ? (float)v : 0.0f;
      fIdx[S + rank] = h;
      fVal[S + rank] = fv;
    }
  }
  __syncthreads();  // fIdx/fVal final

  // export list (k_zs consumes rows >= 2048); scatter f for first-half rows
  if (tid < TOPK) {
    decIdx[row * TOPK + tid] = fIdx[tid];
    decVal[row * TOPK + tid] = fVal[tid];
    if (row < B_ / 2) frow[fIdx[tid] & (H_ - 1)] = fVal[tid];
  }

  // ---- decode: xhat[row,:] = sum_j fVal[j] * WdecT[fIdx[j],:] + b_dec.
  // Parity split (par = j&1 handled by thread half) + j-pairing: each thread
  // processes its 32 j's as 16 pairs, packing (w_j0[col], w_j1[col]) via
  // v_perm and accumulating with v_dot2_f32_f16 (2 MACs/inst).
  const int cb = (tid & 127) * 8;
  const int par = tid >> 7;
  float a[8] = {0.f, 0.f, 0.f, 0.f, 0.f, 0.f, 0.f, 0.f};
#pragma unroll 4
  for (int m = 0; m < 16; ++m) {
    const int j0 = 4 * m + par, j1 = j0 + 2;
    const float v0 = fVal[j0], v1 = fVal[j1];
    const uint4 w0 = *(const uint4*)(WdecT + (size_t)(fIdx[j0] & (H_ - 1)) * F_ + cb);
    const uint4 w1 = *(const uint4*)(WdecT + (size_t)(fIdx[j1] & (H_ - 1)) * F_ + cb);
#if defined(HAVE_FDOT2)
    h16x2 vv; vv[0] = (_Float16)v0; vv[1] = (_Float16)v1;
#pragma unroll
    for (int q = 0; q < 4; ++q) {
      const uint32_t x0 = ((const uint32_t*)&w0)[q];
      const uint32_t x1 = ((const uint32_t*)&w1)[q];
      union { uint32_t u; h16x2 h; } plo, phi;
      plo.u = __builtin_amdgcn_perm(x1, x0, 0x05040100u);  // (x0.lo, x1.lo)
      phi.u = __builtin_amdgcn_perm(x1, x0, 0x07060302u);  // (x0.hi, x1.hi)
      a[q * 2 + 0] = __builtin_amdgcn_fdot2(plo.h, vv, a[q * 2 + 0], false);
      a[q * 2 + 1] = __builtin_amdgcn_fdot2(phi.h, vv, a[q * 2 + 1], false);
    }
#else
#pragma unroll
    for (int q = 0; q < 4; ++q) {
      const uint32_t x0 = ((const uint32_t*)&w0)[q];
      const uint32_t x1 = ((const uint32_t*)&w1)[q];
      a[q * 2 + 0] += v0 * h2f((u16)(x0 & 0xFFFFu)) + v1 * h2f((u16)(x1 & 0xFFFFu));
      a[q * 2 + 1] += v0 * h2f((u16)(x0 >> 16)) + v1 * h2f((u16)(x1 >> 16));
    }
#endif
  }
  if (par) {
#pragma unroll
    for (int k = 0; k < 8; ++k) xs[cb + k] = a[k];  // xs reused as partials
  }
  __syncthreads();
  if (!par) {
    float4 bd0 = *(const float4*)(b_dec + cb);
    float4 bd1 = *(const float4*)(b_dec + cb + 4);
    float4 o0, o1;
    o0.x = a[0] + xs[cb + 0] + bd0.x;
    o0.y = a[1] + xs[cb + 1] + bd0.y;
    o0.z = a[2] + xs[cb + 2] + bd0.z;
    o0.w = a[3] + xs[cb + 3] + bd0.w;
    o1.x = a[4] + xs[cb + 4] + bd1.x;
    o1.y = a[5] + xs[cb + 5] + bd1.y;
    o1.z = a[6] + xs[cb + 6] + bd1.z;
    o1.w = a[7] + xs[cb + 7] + bd1.w;
    float* xp = xhat + (size_t)row * F_ + cb;
    *(float4*)xp = o0;
    *(float4*)(xp + 4) = o1;
  }
}

// ---- K3: second-half zero + scatter (af16 fully dead once selrefdec done) ----
__global__ __launch_bounds__(256) void k_zs(const int* __restrict__ decIdx,
                                            const float* __restrict__ decVal,
                                            float* __restrict__ f) {
  const int row = B_ / 2 + blockIdx.x, tid = threadIdx.x;
  float* frow = f + (size_t)row * H_;
  const f32x4 z4 = {0.f, 0.f, 0.f, 0.f};
  for (int i = tid; i < H_ / 4; i += 256)
    __builtin_nontemporal_store(z4, (f32x4*)frow + i);
  __syncthreads();  // drains vmcnt: zeros committed before scatter
  if (tid < TOPK)
    frow[decIdx[row * TOPK + tid] & (H_ - 1)] = decVal[row * TOPK + tid];
}

extern "C" void kernel_launch(void* const* d_in, const int* in_sizes, int n_in,
                              void* d_out, int out_size, void* d_ws, size_t ws_size,
                              hipStream_t stream) {
  const float* x    = (const float*)d_in[0];
  const float* Wenc = (const float*)d_in[1];
  const float* benc = (const float*)d_in[2];
  const float* Wdec = (const float*)d_in[3];
  const float* bdec = (const float*)d_in[4];

  float* out  = (float*)d_out;
  float* f    = out;                       // [4096][16384] fp32
  float* xhat = out + (size_t)B_ * H_;     // [4096][1024]
  // fp16 'a' lives in the upper half of the f region (fully consumed by
  // k_selrefdec before k_zs zero-fills that half) — no ws growth.
  u16* af16 = (u16*)(f + (size_t)B_ * H_ / 2);  // 128 MB

  char* ws = (char*)d_ws;
  u16*  xbar    = (u16*)ws;                             // 8 MB (fp16)
  u16*  wencb   = (u16*)(ws + (size_t)(8)  * 1048576);  // 32 MB (fp16)
  u16*  wdecT   = (u16*)(ws + (size_t)(40) * 1048576);  // 32 MB (fp16)
  int*  decIdx  = (int*)(ws + (size_t)(76) * 1048576);  // 1 MB
  float* decVal = (float*)(ws + (size_t)(77) * 1048576);// 1 MB

  k_prep<<<36864, 256, 0, stream>>>(x, bdec, Wenc, Wdec, xbar, wencb, wdecT);
  k_gemm<<<dim3(H_ / 128, B_ / 128), 256, 0, stream>>>(xbar, wencb, benc, af16);
  k_selrefdec<<<B_, 256, 0, stream>>>(af16, x, bdec, Wenc, benc, wdecT,
                                      f, xhat, decIdx, decVal);
  k_zs<<<B_ / 2, 256, 0, stream>>>(decIdx, decVal, f);
}

// Round 9
// 692.667 us; speedup vs baseline: 1.0796x; 1.0177x over previous
//
#include <hip/hip_runtime.h>
#include <cstdint>

#define B_ 4096
#define F_ 1024
#define H_ 16384
#define TOPK 64
#define MAXC 192
// 2E: twice the bound on |a_fp16_stored - a_ref| AT THE SELECTION BOUNDARY
// (|a|~1.5). Analytic: fp16-GEMM RMS err ~3e-4 (K=1024, fp32 accum), storage
// rounding <=5e-4 => E=0.006 is ~20-sigma. (Was 0.020; tightened r9 to cut
// the ambiguous-set Wenc gather ~35%.)
#define TWOE 0.012f

#if defined(__has_builtin)
#if __has_builtin(__builtin_amdgcn_fdot2)
#define HAVE_FDOT2 1
#endif
#endif

typedef unsigned short u16;
typedef __attribute__((ext_vector_type(8))) _Float16 f16x8;
typedef __attribute__((ext_vector_type(2))) _Float16 h16x2;
typedef __attribute__((ext_vector_type(8))) unsigned short u16x8;
typedef __attribute__((ext_vector_type(4))) float f32x4;

__device__ __forceinline__ u16 f2bf(float f) {
  union { float f; uint32_t u; } v; v.f = f;
  uint32_t u = v.u;
  uint32_t r = u + 0x7FFFu + ((u >> 16) & 1u);
  return (u16)(r >> 16);
}
__device__ __forceinline__ float bf2f(u16 h) {
  union { uint32_t u; float f; } v; v.u = ((uint32_t)h) << 16; return v.f;
}
__device__ __forceinline__ u16 f2h(float f) {
  union { _Float16 h; u16 u; } v; v.h = (_Float16)f; return v.u;
}
__device__ __forceinline__ float h2f(u16 h) {
  union { _Float16 h; u16 u; } v; v.u = h; return (float)v.h;
}
// packed pair of fp16: zero any negative half (key space: monotone for >=0)
__device__ __forceinline__ uint32_t key2(uint32_t v) {
  uint32_t s = (v >> 15) & 0x00010001u;
  return v & ~(s * 0xFFFFu);
}

__device__ __forceinline__ void async16(const void* g, void* l) {
  __builtin_amdgcn_global_load_lds(
      reinterpret_cast<const __attribute__((address_space(1))) uint32_t*>(
          reinterpret_cast<uintptr_t>(g)),
      reinterpret_cast<__attribute__((address_space(3))) uint32_t*>(
          reinterpret_cast<uintptr_t>(l)),
      16, 0, 0);
}

// ---- K0: merged prep (xbar | cast | transpose) — one launch, one BW wave.
__global__ __launch_bounds__(256) void k_prep(const float* __restrict__ x,
                                              const float* __restrict__ b_dec,
                                              const float* __restrict__ Wenc,
                                              const float* __restrict__ Wdec,
                                              u16* __restrict__ xbar,
                                              u16* __restrict__ wencb,
                                              u16* __restrict__ wdecT) {
  __shared__ float tile[32][33];
  const int b = blockIdx.x, tid = threadIdx.x;
  if (b < 4096) {  // xbar
    int i = b * 256 + tid;
    int base = i * 4;
    int col = base & (F_ - 1);
    float4 xv = *(const float4*)(x + base);
    float4 bv = *(const float4*)(b_dec + col);
    ushort4 o;
    o.x = f2h(xv.x - bv.x); o.y = f2h(xv.y - bv.y);
    o.z = f2h(xv.z - bv.z); o.w = f2h(xv.w - bv.w);
    *(ushort4*)(xbar + base) = o;
  } else if (b < 20480) {  // cast W_enc
    size_t base = ((size_t)(b - 4096) * 256 + tid) * 4;
    float4 v = *(const float4*)(Wenc + base);
    ushort4 o; o.x = f2h(v.x); o.y = f2h(v.y); o.z = f2h(v.z); o.w = f2h(v.w);
    *(ushort4*)(wencb + base) = o;
  } else {  // transpose W_dec -> fp16 W_decT
    const int t = b - 20480;
    const int hb = (t & 511) * 32, fb = (t >> 9) * 32;
    const int tx = tid & 31, ty = tid >> 5;  // ty 0..7
#pragma unroll
    for (int i = 0; i < 32; i += 8)
      tile[ty + i][tx] = Wdec[(size_t)(fb + ty + i) * H_ + hb + tx];
    __syncthreads();
#pragma unroll
    for (int i = 0; i < 32; i += 8)
      wdecT[(size_t)(hb + ty + i) * F_ + fb + tx] = f2h(tile[tx][ty + i]);
  }
}

// ---- K1: fp16 MFMA GEMM, RING-3 counted-vmcnt pipeline, fully unrolled.
// De-confounded retry of round 3: that attempt regressed from (a) the XCD
// stripe blowing A's per-XCD L2 set (FETCH 131->502 MB) and (b) runtime
// stage offsets (the 58%-VALUBusy trap r6 exposed). This version keeps the
// original 2D raster + full unroll (t%3 buffers and (t+2)*32 offsets all
// compile-time). Sync per tile: counted "s_waitcnt vmcnt(4)" (previous
// tile's 4 loads land; next tile's 4 stay IN FLIGHT across the barrier) +
// raw s_barrier — never a vmcnt(0) drain in steady state (the m97 ~20%
// stall). Race audit (same scheme as r3, which was correctness-clean):
// ds_reads are consumed by MFMAs before each barrier (compiler lgkmcnt);
// STAGE targets the buffer last read one full barrier interval earlier;
// sched_barrier(0) fences pin the order around each wait+barrier.
__device__ __forceinline__ void gemm_step(const u16* __restrict__ bA,
                                          const u16* __restrict__ bB,
                                          int aoff, int boff, int kcp,
                                          f32x4 (&acc)[4][4]) {
  f16x8 av[4], bv[4];
#pragma unroll
  for (int i = 0; i < 4; ++i)
    av[i] = *(const f16x8*)&bA[(aoff + i * 16) * 32 + kcp];
#pragma unroll
  for (int j = 0; j < 4; ++j)
    bv[j] = *(const f16x8*)&bB[(boff + j * 16) * 32 + kcp];
#pragma unroll
  for (int i = 0; i < 4; ++i)
#pragma unroll
    for (int j = 0; j < 4; ++j)
      acc[i][j] = __builtin_amdgcn_mfma_f32_16x16x32_f16(av[i], bv[j], acc[i][j], 0, 0, 0);
}

__global__ __launch_bounds__(256) void k_gemm(const u16* __restrict__ A,
                                              const u16* __restrict__ Bm,
                                              const float* __restrict__ b_enc,
                                              u16* __restrict__ Cf16) {
  __shared__ u16 lA[3][128 * 32];  // 24 KB
  __shared__ u16 lB[3][128 * 32];  // 24 KB  (48 KB total -> 3 blocks/CU)
  const int tid = threadIdx.x;
  const int lane = tid & 63, wave = tid >> 6;
  const int wm = wave >> 1, wn = wave & 1;
  const int bx = blockIdx.x, by = blockIdx.y;

  const int kcs = (tid & 3) ^ ((tid >> 3) & 3);  // swizzled source chunk
  const u16* gA0 = A + (size_t)(by * 128 + (tid >> 2)) * F_ + kcs * 8;
  const u16* gA1 = gA0 + 64 * F_;
  const u16* gB0 = Bm + (size_t)(bx * 128 + (tid >> 2)) * F_ + kcs * 8;
  const u16* gB1 = gB0 + 64 * F_;

#define STAGE(b_, k0_)                             \
  {                                                \
    async16(gA0 + (k0_), &lA[b_][tid * 8]);        \
    async16(gA1 + (k0_), &lA[b_][tid * 8 + 2048]); \
    async16(gB0 + (k0_), &lB[b_][tid * 8]);        \
    async16(gB1 + (k0_), &lB[b_][tid * 8 + 2048]); \
  }
#define SYNCN(n_)                                          \
  {                                                        \
    asm volatile("s_waitcnt vmcnt(" #n_ ")" ::: "memory"); \
    __builtin_amdgcn_sched_barrier(0);                     \
    __builtin_amdgcn_s_barrier();                          \
    __builtin_amdgcn_sched_barrier(0);                     \
  }

  f32x4 acc[4][4] = {};
  const int lm = lane & 15;
  const int kcp = (((lane >> 4) ^ ((lm >> 1) & 3))) * 8;  // swizzled read offset
  const int aoff = wm * 64 + lm, boff = wn * 64 + lm;

  // prologue: tiles 0,1 in flight; wait own tile-0 loads, barrier = all waves'
  STAGE(0, 0);
  STAGE(1, 32);
  SYNCN(4);

  // fully unrolled ring-3: buffers and offsets compile-time
#pragma unroll
  for (int t = 0; t < 32; ++t) {
    if (t + 2 < 32) STAGE((t + 2) % 3, (t + 2) * 32);
    gemm_step(lA[t % 3], lB[t % 3], aoff, boff, kcp, acc);
    if (t < 31) {
      if (t + 2 < 32) SYNCN(4)   // prev-staged tile landed; newest stays in flight
      else SYNCN(0)              // t==30: only tile 31 outstanding
    }
  }
#undef STAGE
#undef SYNCN

#pragma unroll
  for (int i = 0; i < 4; ++i) {
    int rowg = by * 128 + wm * 64 + i * 16 + (lane >> 4) * 4;
#pragma unroll
    for (int j = 0; j < 4; ++j) {
      int colg = bx * 128 + wn * 64 + j * 16 + lm;
      float be = b_enc[colg];
      u16* cp = Cf16 + (size_t)rowg * H_ + colg;
#pragma unroll
      for (int r = 0; r < 4; ++r)
        cp[(size_t)r * H_] = f2h(acc[i][j][r] + be);
    }
  }
}

// ---- K2: fused select + refine + decode (round-8 structure; TWOE=0.012) ----
__global__ __launch_bounds__(256) void k_selrefdec(const u16* __restrict__ af16,
                                                   const float* __restrict__ x,
                                                   const float* __restrict__ b_dec,
                                                   const float* __restrict__ Wenc,
                                                   const float* __restrict__ b_enc,
                                                   const u16* __restrict__ WdecT,
                                                   float* __restrict__ f,
                                                   float* __restrict__ xhat,
                                                   int* __restrict__ decIdx,
                                                   float* __restrict__ decVal) {
  const int row = blockIdx.x, tid = threadIdx.x;
  const int lane = tid & 63, wave = tid >> 6;
  __shared__ float wbuf[4][2][F_];  // 32 KB refine gather buffers
  __shared__ float xs[F_];          // 4 KB; reused as decode parity partials
  __shared__ double vals[MAXC];     // 1.5 KB
  __shared__ float bes[MAXC];
  __shared__ int idxs[MAXC];
  __shared__ int fIdx[TOPK];        // final top-64 (LDS-resident for decode)
  __shared__ float fVal[TOPK];
  __shared__ int s_cnt8[2][4];
  __shared__ int s_sure, s_amb;

  if (tid == 0) { s_sure = 0; s_amb = 0; idxs[0] = 0; }
  if (tid < TOPK) { fIdx[tid] = 0; fVal[tid] = 0.f; }
  for (int k = tid; k < F_; k += 256)
    xs[k] = x[(size_t)row * F_ + k] - b_dec[k];

  float* frow = f + (size_t)row * H_;
  if (row < B_ / 2) {  // first half: zero own row now (hidden under search)
    const f32x4 z4 = {0.f, 0.f, 0.f, 0.f};
    for (int i = tid; i < H_ / 4; i += 256)
      __builtin_nontemporal_store(z4, (f32x4*)frow + i);
  }

  // row -> registers as sort keys (64 halfs = 32 packed u32 per thread)
  uint32_t pr[32];
  {
    const uint4* arow16 = (const uint4*)(af16 + (size_t)row * H_);
#pragma unroll
    for (int j = 0; j < 8; ++j) {
      uint4 v = arow16[tid + 256 * j];
      pr[j * 4 + 0] = key2(v.x);
      pr[j * 4 + 1] = key2(v.y);
      pr[j * 4 + 2] = key2(v.z);
      pr[j * 4 + 3] = key2(v.w);
    }
  }

  // binary search, early-stopped: bracket v64key within [lo,hi), hi-lo<=8
  uint32_t lo = 0, hi = 0x7C00;
  int it = 0;
  while (hi - lo > 8) {  // 12 iterations
    const uint32_t mid = (lo + hi) >> 1;
    int c = 0;
#pragma unroll
    for (int r = 0; r < 32; ++r) {
      c += ((pr[r] & 0xFFFFu) >= mid);
      c += ((pr[r] >> 16) >= mid);
    }
#pragma unroll
    for (int off = 32; off > 0; off >>= 1) c += __shfl_xor(c, off);
    if (lane == 0) s_cnt8[it & 1][wave] = c;
    __syncthreads();
    const int* scp = s_cnt8[it & 1];
    const int tot = scp[0] + scp[1] + scp[2] + scp[3];
    if (tot >= TOPK) lo = mid; else hi = mid;
    ++it;  // double-buffered slot: safe with one barrier per iter
  }
  // v64key in [lo,hi): sc/al from the bracket edges stay conservative.
  const float scf = h2f((u16)hi) + TWOE;  // stored > scf: surely in top-64
  const float alf = h2f((u16)lo) - TWOE;  // stored < alf: surely out
  const int ksc = f2h(scf);                       // scf > 0 always
  const int kal = (alf <= 0.f) ? 0 : (int)f2h(alf);

#pragma unroll
  for (int j = 0; j < 8; ++j) {
#pragma unroll
    for (int w = 0; w < 4; ++w) {
      const uint32_t v = pr[j * 4 + w];
      const int ib = (tid + 256 * j) * 8 + w * 2;
      const int k0 = (int)(v & 0xFFFFu), k1 = (int)(v >> 16);
      if (k0 > ksc) {
        int p = atomicAdd(&s_sure, 1);
        if (p < TOPK) { fIdx[p] = ib; fVal[p] = h2f((u16)k0); }  // >sc>0
      } else if (k0 >= kal) {
        int p = atomicAdd(&s_amb, 1);
        if (p < MAXC) idxs[p] = ib;
      }
      if (k1 > ksc) {
        int p = atomicAdd(&s_sure, 1);
        if (p < TOPK) { fIdx[p] = ib + 1; fVal[p] = h2f((u16)k1); }
      } else if (k1 >= kal) {
        int p = atomicAdd(&s_amb, 1);
        if (p < MAXC) idxs[p] = ib + 1;
      }
    }
  }
  __syncthreads();
  const int S = s_sure < TOPK ? s_sure : TOPK;
  const int cnt = s_amb < MAXC ? s_amb : MAXC;
  for (int c = tid; c < cnt; c += 256) bes[c] = b_enc[idxs[c]];
  __syncthreads();

  // candidate-invariant x slice -> fp32 registers (last read of xs as xbar)
  float xr[16];
#pragma unroll
  for (int ch = 0; ch < 4; ++ch)
#pragma unroll
    for (int j = 0; j < 4; ++j)
      xr[ch * 4 + j] = xs[ch * 256 + lane * 4 + j];

#define ISSUE_ROW(c_, b_)                                                  \
  {                                                                        \
    int cc_ = (c_) < cnt ? (c_) : 0;                                       \
    const float* src_ = Wenc + (size_t)idxs[cc_] * F_ + lane * 4;          \
    float* dst_ = &wbuf[wave][(b_)][lane * 4];                             \
    async16(src_ + 0, dst_ + 0);                                           \
    async16(src_ + 256, dst_ + 256);                                       \
    async16(src_ + 512, dst_ + 512);                                       \
    async16(src_ + 768, dst_ + 768);                                       \
  }

  const int nIter = (cnt - wave + 3) / 4;
  ISSUE_ROW(wave, 0);
  ISSUE_ROW(wave + 4, 1);

  for (int i = 0; i < nIter; ++i) {
    const int c = wave + i * 4;
    const int bsel = i & 1;
    asm volatile("s_waitcnt vmcnt(4)" ::: "memory");
    __builtin_amdgcn_sched_barrier(0);

    const float4* wr = (const float4*)wbuf[wave][bsel];
    double s = 0.0;
#pragma unroll
    for (int ch = 0; ch < 4; ++ch) {
      float4 wv = wr[ch * 64 + lane];
      s = fma((double)xr[ch * 4 + 0], (double)wv.x, s);
      s = fma((double)xr[ch * 4 + 1], (double)wv.y, s);
      s = fma((double)xr[ch * 4 + 2], (double)wv.z, s);
      s = fma((double)xr[ch * 4 + 3], (double)wv.w, s);
    }
    __builtin_amdgcn_sched_barrier(0);
    ISSUE_ROW(wave + (i + 2) * 4, bsel);

#pragma unroll
    for (int off = 32; off > 0; off >>= 1) s += __shfl_xor(s, off);
    if (lane == 0 && c < cnt) vals[c] = s + (double)bes[c];
  }
#undef ISSUE_ROW
  __syncthreads();

  // exact ranking among ambiguous; top (TOPK - S) win slots S..TOPK-1
  const int Kp = TOPK - S;
  for (int c = tid; c < cnt; c += 256) {
    const double v = vals[c];
    const int h = idxs[c];
    int rank = 0;
    for (int o = 0; o < cnt; ++o) {
      double vo = vals[o];
      rank += (vo > v) || (vo == v && idxs[o] < h);  // jax tie-break
    }
    if (rank < Kp) {
      float fv = v > 0.0 ? (float)v : 0.0f;
      fIdx[S + rank] = h;
      fVal[S + rank] = fv;
    }
  }
  __syncthreads();  // fIdx/fVal final

  // export list (k_zs consumes rows >= 2048); scatter f for first-half rows
  if (tid < TOPK) {
    decIdx[row * TOPK + tid] = fIdx[tid];
    decVal[row * TOPK + tid] = fVal[tid];
    if (row < B_ / 2) frow[fIdx[tid] & (H_ - 1)] = fVal[tid];
  }

  // ---- decode: xhat[row,:] = sum_j fVal[j] * WdecT[fIdx[j],:] + b_dec.
  const int cb = (tid & 127) * 8;
  const int par = tid >> 7;
  float a[8] = {0.f, 0.f, 0.f, 0.f, 0.f, 0.f, 0.f, 0.f};
#pragma unroll 4
  for (int m = 0; m < 16; ++m) {
    const int j0 = 4 * m + par, j1 = j0 + 2;
    const float v0 = fVal[j0], v1 = fVal[j1];
    const uint4 w0 = *(const uint4*)(WdecT + (size_t)(fIdx[j0] & (H_ - 1)) * F_ + cb);
    const uint4 w1 = *(const uint4*)(WdecT + (size_t)(fIdx[j1] & (H_ - 1)) * F_ + cb);
#if defined(HAVE_FDOT2)
    h16x2 vv; vv[0] = (_Float16)v0; vv[1] = (_Float16)v1;
#pragma unroll
    for (int q = 0; q < 4; ++q) {
      const uint32_t x0 = ((const uint32_t*)&w0)[q];
      const uint32_t x1 = ((const uint32_t*)&w1)[q];
      union { uint32_t u; h16x2 h; } plo, phi;
      plo.u = __builtin_amdgcn_perm(x1, x0, 0x05040100u);  // (x0.lo, x1.lo)
      phi.u = __builtin_amdgcn_perm(x1, x0, 0x07060302u);  // (x0.hi, x1.hi)
      a[q * 2 + 0] = __builtin_amdgcn_fdot2(plo.h, vv, a[q * 2 + 0], false);
      a[q * 2 + 1] = __builtin_amdgcn_fdot2(phi.h, vv, a[q * 2 + 1], false);
    }
#else
#pragma unroll
    for (int q = 0; q < 4; ++q) {
      const uint32_t x0 = ((const uint32_t*)&w0)[q];
      const uint32_t x1 = ((const uint32_t*)&w1)[q];
      a[q * 2 + 0] += v0 * h2f((u16)(x0 & 0xFFFFu)) + v1 * h2f((u16)(x1 & 0xFFFFu));
      a[q * 2 + 1] += v0 * h2f((u16)(x0 >> 16)) + v1 * h2f((u16)(x1 >> 16));
    }
#endif
  }
  if (par) {
#pragma unroll
    for (int k = 0; k < 8; ++k) xs[cb + k] = a[k];  // xs reused as partials
  }
  __syncthreads();
  if (!par) {
    float4 bd0 = *(const float4*)(b_dec + cb);
    float4 bd1 = *(const float4*)(b_dec + cb + 4);
    float4 o0, o1;
    o0.x = a[0] + xs[cb + 0] + bd0.x;
    o0.y = a[1] + xs[cb + 1] + bd0.y;
    o0.z = a[2] + xs[cb + 2] + bd0.z;
    o0.w = a[3] + xs[cb + 3] + bd0.w;
    o1.x = a[4] + xs[cb + 4] + bd1.x;
    o1.y = a[5] + xs[cb + 5] + bd1.y;
    o1.z = a[6] + xs[cb + 6] + bd1.z;
    o1.w = a[7] + xs[cb + 7] + bd1.w;
    float* xp = xhat + (size_t)row * F_ + cb;
    *(float4*)xp = o0;
    *(float4*)(xp + 4) = o1;
  }
}

// ---- K3: second-half zero + scatter (af16 fully dead once selrefdec done) ----
__global__ __launch_bounds__(256) void k_zs(const int* __restrict__ decIdx,
                                            const float* __restrict__ decVal,
                                            float* __restrict__ f) {
  const int row = B_ / 2 + blockIdx.x, tid = threadIdx.x;
  float* frow = f + (size_t)row * H_;
  const f32x4 z4 = {0.f, 0.f, 0.f, 0.f};
  for (int i = tid; i < H_ / 4; i += 256)
    __builtin_nontemporal_store(z4, (f32x4*)frow + i);
  __syncthreads();  // drains vmcnt: zeros committed before scatter
  if (tid < TOPK)
    frow[decIdx[row * TOPK + tid] & (H_ - 1)] = decVal[row * TOPK + tid];
}

extern "C" void kernel_launch(void* const* d_in, const int* in_sizes, int n_in,
                              void* d_out, int out_size, void* d_ws, size_t ws_size,
                              hipStream_t stream) {
  const float* x    = (const float*)d_in[0];
  const float* Wenc = (const float*)d_in[1];
  const float* benc = (const float*)d_in[2];
  const float* Wdec = (const float*)d_in[3];
  const float* bdec = (const float*)d_in[4];

  float* out  = (float*)d_out;
  float* f    = out;                       // [4096][16384] fp32
  float* xhat = out + (size_t)B_ * H_;     // [4096][1024]
  // fp16 'a' lives in the upper half of the f region (fully consumed by
  // k_selrefdec before k_zs zero-fills that half) — no ws growth.
  u16* af16 = (u16*)(f + (size_t)B_ * H_ / 2);  // 128 MB

  char* ws = (char*)d_ws;
  u16*  xbar    = (u16*)ws;                             // 8 MB (fp16)
  u16*  wencb   = (u16*)(ws + (size_t)(8)  * 1048576);  // 32 MB (fp16)
  u16*  wdecT   = (u16*)(ws + (size_t)(40) * 1048576);  // 32 MB (fp16)
  int*  decIdx  = (int*)(ws + (size_t)(76) * 1048576);  // 1 MB
  float* decVal = (float*)(ws + (size_t)(77) * 1048576);// 1 MB

  k_prep<<<36864, 256, 0, stream>>>(x, bdec, Wenc, Wdec, xbar, wencb, wdecT);
  k_gemm<<<dim3(H_ / 128, B_ / 128), 256, 0, stream>>>(xbar, wencb, benc, af16);
  k_selrefdec<<<B_, 256, 0, stream>>>(af16, x, bdec, Wenc, benc, wdecT,
                                      f, xhat, decIdx, decVal);
  k_zs<<<B_ / 2, 256, 0, stream>>>(decIdx, decVal, f);
}